// Round 1
// baseline (548.848 us; speedup 1.0000x reference)
//
#include <hip/hip_runtime.h>
#include <cmath>

typedef unsigned short u16;
using short8 = __attribute__((ext_vector_type(8))) short;   // 8 x bf16
using f32x4  = __attribute__((ext_vector_type(4))) float;   // MFMA acc

// ---------- helpers ----------
__device__ __forceinline__ u16 f2bf(float f) {  // fp32 -> bf16 RNE
  union { float f; unsigned u; } c; c.f = f;
  unsigned r = c.u + 0x7fffu + ((c.u >> 16) & 1u);
  return (u16)(r >> 16);
}
__device__ __forceinline__ float bf2f(u16 b) {
  union { unsigned u; float f; } c; c.u = ((unsigned)b) << 16;
  return c.f;
}

__device__ __forceinline__ void gld_lds16(void* lds, const void* g) {
  __builtin_amdgcn_global_load_lds(
      (const __attribute__((address_space(1))) void*)g,
      (__attribute__((address_space(3))) void*)lds, 16, 0, 0);
}

// fast GELU (tanh approx, max err ~1e-3 << bf16 threshold)
__device__ __forceinline__ float gelu_fast(float t) {
  float u = 0.7978845608f * t * (1.f + 0.044715f * t * t);
  float th = 1.f - 2.f / (__expf(2.f * u) + 1.f);
  return 0.5f * t * (1.f + th);
}

// ---------- fp32 -> bf16 convert ----------
__global__ __launch_bounds__(256) void cvt_bf16(const float* __restrict__ in,
                                                u16* __restrict__ out, int n4) {
  int i = blockIdx.x * 256 + threadIdx.x;
  if (i >= n4) return;
  float4 v = ((const float4*)in)[i];
  ushort4 o;
  o.x = f2bf(v.x); o.y = f2bf(v.y); o.z = f2bf(v.z); o.w = f2bf(v.w);
  ((ushort4*)out)[i] = o;
}

// fp32 -> bf16 into strided (padded) rows
__global__ __launch_bounds__(256) void cvt_pad(const float* __restrict__ in,
                                               u16* __restrict__ out,
                                               int incols4, int outstride, int n4) {
  int i = blockIdx.x * 256 + threadIdx.x;
  if (i >= n4) return;
  int row = i / incols4, c = i - row * incols4;
  float4 v = ((const float4*)in)[i];
  ushort4 o;
  o.x = f2bf(v.x); o.y = f2bf(v.y); o.z = f2bf(v.z); o.w = f2bf(v.w);
  *(ushort4*)&out[(size_t)row * outstride + c * 4] = o;
}

// ---------- relative-position bias table ----------
__global__ __launch_bounds__(256) void btab_kernel(const float* __restrict__ rel_embed,
                                                   float* __restrict__ btab) {
  int idx = blockIdx.x * 256 + threadIdx.x;
  if (idx >= 16 * 2048) return;
  int h = idx >> 11;
  int d = idx & 2047;
  if (d >= 2047) return;
  int rel = d - 1023;
  int bucket = (rel > 0) ? 160 : 0;
  int ar = rel < 0 ? -rel : rel;
  if (ar < 80) {
    bucket += ar;
  } else {
    int large = 80 + (int)(logf((float)ar / 80.0f) / 2.3025851f * 80.0f);
    if (large > 159) large = 159;
    bucket += large;
  }
  btab[h * 2048 + d] = rel_embed[bucket * 16 + h];
}

// ---------- gate ----------
__global__ __launch_bounds__(256) void gate_kernel(const float* __restrict__ x,
                                                   const float* __restrict__ Wg,
                                                   const float* __restrict__ bg,
                                                   const float* __restrict__ gc,
                                                   float* __restrict__ gate_out) {
  int gw = blockIdx.x * 4 + (threadIdx.x >> 6);
  int lane = threadIdx.x & 63;
  int s = gw & 1023, bh = gw >> 10, b = bh >> 4, h = bh & 15;
  float wA = Wg[lane] + Wg[64 + lane] + Wg[128 + lane] + Wg[192 + lane];
  float wB = Wg[256 + lane] + Wg[320 + lane] + Wg[384 + lane] + Wg[448 + lane];
  float xv = x[((size_t)(b * 1024 + s)) * 1024 + h * 64 + lane];
  float pa = xv * wA, pb = xv * wB;
  #pragma unroll
  for (int m = 1; m < 64; m <<= 1) {
    pa += __shfl_xor(pa, m, 64);
    pb += __shfl_xor(pb, m, 64);
  }
  if (lane == 0) {
    float bgA = bg[0] + bg[1] + bg[2] + bg[3];
    float bgB = bg[4] + bg[5] + bg[6] + bg[7];
    float ga = 1.f / (1.f + expf(-(pa + bgA)));
    float gb = 1.f / (1.f + expf(-(pb + bgB)));
    gate_out[(size_t)bh * 1024 + s] = ga * (gb * gc[h] - 1.f) + 2.f;
  }
}

// ---------- V transpose: vt[bh][d][s] ----------
__global__ __launch_bounds__(256) void vtrans_kernel(const u16* __restrict__ vb,
                                                     u16* __restrict__ vt) {
  __shared__ u16 tile[64 * 65];
  int bh = blockIdx.y, b = bh >> 4, h = bh & 15;
  int s0 = blockIdx.x * 64;
  int tid = threadIdx.x;
  int r = tid >> 3, c = (tid & 7) * 8;
  #pragma unroll
  for (int p = 0; p < 2; ++p) {
    int s = p * 32 + r;
    uint4 vv = *(const uint4*)&vb[((size_t)(b * 1024 + s0 + s)) * 1024 + h * 64 + c];
    const u16* pv = (const u16*)&vv;
    #pragma unroll
    for (int e = 0; e < 8; ++e) tile[(c + e) * 65 + s] = pv[e];
  }
  __syncthreads();
  int d = tid & 63, jc0 = tid >> 6;
  #pragma unroll
  for (int jc = jc0; jc < 8; jc += 4) {
    u16 tmp[8];
    #pragma unroll
    for (int e = 0; e < 8; ++e) tmp[e] = tile[d * 65 + jc * 8 + e];
    *(uint4*)&vt[((size_t)(bh * 64 + d)) * 1024 + s0 + jc * 8] = *(uint4*)tmp;
  }
}

// ---------- GEMM 128x128 (legacy 3-stage) ----------
// Kept for small shapes: Wo (split-K2), adapter-down (N=256, bn0=4096).
template <int MODE>
__global__ __launch_bounds__(256, 3) void gemm_bt(
    const u16* __restrict__ A, const u16* __restrict__ Bw,
    int K, int Ksub, int N, int bn0,
    const float* __restrict__ bias0, const float* __restrict__ bias1,
    const float* __restrict__ bias2,
    float* __restrict__ outf,
    u16* __restrict__ ob0, u16* __restrict__ ob1, u16* __restrict__ ob2) {
  __shared__ __align__(16) u16 As[3][128 * 32];
  __shared__ __align__(16) u16 Bs[3][128 * 32];
  const int tid = threadIdx.x;
  const int lane = tid & 63, wave = tid >> 6;
  const int quad = lane >> 4, l16 = lane & 15;
  const int bm = blockIdx.x * 128, bn = blockIdx.y * 128;
  const int kz = blockIdx.z;
  const int nsteps = Ksub >> 5;
  const int wm = (wave & 1) * 64, wn = (wave >> 1) * 64;
  const int sr = lane & 15, skc = (lane >> 4) * 8;

  const u16* a0 = A + (size_t)(bm + wave * 32 + sr) * K + kz * Ksub + skc;
  const u16* b0 = Bw + (size_t)(bn + wave * 32 + sr) * K + kz * Ksub + skc;
  const size_t ra = (size_t)16 * K;

  f32x4 acc[4][4] = {};

  #pragma unroll
  for (int t = 0; t < 2; ++t) {
    gld_lds16(&As[0][(wave * 2 + t) * 512], a0 + t * ra);
    gld_lds16(&Bs[0][(wave * 2 + t) * 512], b0 + t * ra);
  }
  if (nsteps > 1) {
    #pragma unroll
    for (int t = 0; t < 2; ++t) {
      gld_lds16(&As[1][(wave * 2 + t) * 512], a0 + t * ra + 32);
      gld_lds16(&Bs[1][(wave * 2 + t) * 512], b0 + t * ra + 32);
    }
  }

  int cur = 0, nxt2 = 2;
  for (int ks = 0; ks < nsteps; ++ks) {
    if (ks + 1 < nsteps) asm volatile("s_waitcnt vmcnt(4)" ::: "memory");
    else                 asm volatile("s_waitcnt vmcnt(0)" ::: "memory");
    __builtin_amdgcn_s_barrier();
    if (ks + 2 < nsteps) {
      int ko = (ks + 2) * 32;
      #pragma unroll
      for (int t = 0; t < 2; ++t) {
        gld_lds16(&As[nxt2][(wave * 2 + t) * 512], a0 + t * ra + ko);
        gld_lds16(&Bs[nxt2][(wave * 2 + t) * 512], b0 + t * ra + ko);
      }
    }
    const u16* Ap = As[cur];
    const u16* Bp = Bs[cur];
    short8 af[4], bf[4];
    #pragma unroll
    for (int mi = 0; mi < 4; ++mi)
      af[mi] = *(const short8*)&Ap[((wm >> 4) + mi) * 512 + quad * 128 + l16 * 8];
    #pragma unroll
    for (int ni = 0; ni < 4; ++ni)
      bf[ni] = *(const short8*)&Bp[((wn >> 4) + ni) * 512 + quad * 128 + l16 * 8];
    #pragma unroll
    for (int mi = 0; mi < 4; ++mi)
      #pragma unroll
      for (int ni = 0; ni < 4; ++ni)
        acc[mi][ni] = __builtin_amdgcn_mfma_f32_16x16x32_bf16(af[mi], bf[ni], acc[mi][ni], 0, 0, 0);
    cur = (cur == 2) ? 0 : cur + 1;
    nxt2 = (nxt2 == 2) ? 0 : nxt2 + 1;
  }

  float* outp = outf + (size_t)kz * 4194304;

  #pragma unroll
  for (int mi = 0; mi < 4; ++mi) {
    #pragma unroll
    for (int ni = 0; ni < 4; ++ni) {
      int col = bn + bn0 + wn + ni * 16 + l16;
      #pragma unroll
      for (int r = 0; r < 4; ++r) {
        int m = bm + wm + mi * 16 + quad * 4 + r;
        float v = acc[mi][ni][r];
        if constexpr (MODE == 0) {
          int seg = col >> 10;
          int nloc = col & 1023;
          const float* bs = seg == 0 ? bias0 : (seg == 1 ? bias1 : bias2);
          u16* dst = seg == 0 ? ob0 : (seg == 1 ? ob1 : ob2);
          v += bs[nloc];
          if (seg == 0) v *= 0.125f;
          dst[(size_t)m * 1024 + nloc] = f2bf(v);
        } else if constexpr (MODE == 2) {
          if (col < 4096) {
            float t = v + bias0[col];
            ob0[(size_t)m * 4352 + col] = f2bf(gelu_fast(t));
          } else {
            float t = v + bias1[col - 4096];
            float e = t > 0.f ? t : (__expf(t) - 1.f);
            ob0[(size_t)m * 4352 + col] = f2bf(e);
          }
        } else {
          outp[(size_t)m * N + col] = v;
        }
      }
    }
  }
}

// ---------- GEMM 256x256, BK=64, 8 waves, 8-phase counted-vmcnt pipeline ----------
// C[m,n] = sum_k A[m,k]*Bw[n,k]. 512 threads = 8 waves (2M x 4N), wave tile
// 128x64, acc[8][4] 16x16 frags. LDS 128KB = 2 K-tile buffers x (A 32K + B 32K),
// staged as k-half-tiles (16KB), one half per phase, 2 x global_load_lds/thread.
// LDS layout per (buf, A/B, khalf) region: [256 rows][32 cols], row = 64B,
// 16B chunks XOR-swizzled: chunk_pos = chunk ^ ((row>>1)&3)  -> ds_read_b128
// frag reads are 2-way bank aliased (free); staging keeps LINEAR LDS dest and
// applies the inverse (same) permutation to the global source (involution).
// Main loop: vmcnt(8) (4 half-tiles in flight) before the closing barrier of
// even phases; never drains. Peeled last iter drains 8 -> 4 -> 0.
// MODE 0: QKV epilogue (seg bias + q*0.125, bf16 x3)
// MODE 2: FF1 gelu -> ffadp (stride 4352, cols < 4096)
// MODE 3: fp32 partials (split-K), stride 4194304 floats per kz
#define VMCNT(n) asm volatile("s_waitcnt vmcnt(" #n ")" ::: "memory")
#define NOOPST ((void)0)

#define G256_LDA(BUF, KK, MH)                                               \
  af_[0] = *(const short8*)&lds[BUF][0][KK][aBase + (MH) * 2048 + 0];       \
  af_[1] = *(const short8*)&lds[BUF][0][KK][aBase + (MH) * 2048 + 512];     \
  af_[2] = *(const short8*)&lds[BUF][0][KK][aBase + (MH) * 2048 + 1024];    \
  af_[3] = *(const short8*)&lds[BUF][0][KK][aBase + (MH) * 2048 + 1536];
#define G256_LDB(BUF, KK)                                                   \
  bf_[0] = *(const short8*)&lds[BUF][1][KK][bBase + 0];                     \
  bf_[1] = *(const short8*)&lds[BUF][1][KK][bBase + 512];                   \
  bf_[2] = *(const short8*)&lds[BUF][1][KK][bBase + 1024];                  \
  bf_[3] = *(const short8*)&lds[BUF][1][KK][bBase + 1536];
#define G256_MFMA(MH)                                                       \
  _Pragma("unroll") for (int mi = 0; mi < 4; ++mi)                          \
  _Pragma("unroll") for (int ni = 0; ni < 4; ++ni)                          \
    acc[(MH) * 4 + mi][ni] = __builtin_amdgcn_mfma_f32_16x16x32_bf16(       \
        af_[mi], bf_[ni], acc[(MH) * 4 + mi][ni], 0, 0, 0);
#define G256_PHASE(BUF, KK, MH, DOB, STAGE, WAIT)                           \
  {                                                                         \
    G256_LDA(BUF, KK, MH)                                                   \
    if (DOB) { G256_LDB(BUF, KK) }                                          \
    STAGE;                                                                  \
    __builtin_amdgcn_s_barrier();                                           \
    asm volatile("s_waitcnt lgkmcnt(0)" ::: "memory");                      \
    __builtin_amdgcn_s_setprio(1);                                          \
    G256_MFMA(MH)                                                           \
    __builtin_amdgcn_s_setprio(0);                                          \
    WAIT;                                                                   \
    __builtin_amdgcn_s_barrier();                                           \
  }

template <int MODE>
__global__ __launch_bounds__(512, 2) void gemm256(
    const u16* __restrict__ A, const u16* __restrict__ Bw,
    int lda, int ldb, int kt_hi, int kt_lo, int z_hi,
    const float* __restrict__ bias0, const float* __restrict__ bias1,
    const float* __restrict__ bias2,
    float* __restrict__ outf, float* __restrict__ outf2, int ldo,
    u16* __restrict__ ob0, u16* __restrict__ ob1, u16* __restrict__ ob2) {
  __shared__ __align__(16) u16 lds[2][2][2][8192];

  const int tid = threadIdx.x;
  const int lane = tid & 63, wave = tid >> 6;
  const int quad = lane >> 4, l16 = lane & 15;
  const int wm = wave >> 2, wn = wave & 3;

  // XCD-aware bijective swizzle (all launch grids are multiples of 8 blocks)
  const int gx = gridDim.x, gy = gridDim.y;
  int flat = blockIdx.x + gx * (blockIdx.y + gy * blockIdx.z);
  const int cpx = (gx * gy * gridDim.z) >> 3;
  flat = (flat & 7) * cpx + (flat >> 3);
  const int bmi = flat % gx;
  int rest = flat / gx;
  const int bni = rest % gy;
  const int kz = rest / gy;

  const int bm = bmi * 256, bn = bni * 256;
  const int nkt = (kz < z_hi) ? kt_hi : kt_lo;
  const int ktb = (kz < z_hi) ? kz * kt_hi : z_hi * kt_hi + (kz - z_hi) * kt_lo;
  const int nIter = nkt >> 1;

  // staging geometry: lane l stages row (wave*16 + l/4) (+128 for 2nd load),
  // 16B chunk (l&3)^((row>>1)&3) of the 32-col k-half -> linear LDS dest.
  const int srow = wave * 16 + (lane >> 2);
  const int sk = (((lane & 3) ^ ((lane >> 3) & 3)) << 3);
  const u16* aG = A + (size_t)(bm + srow) * lda + (size_t)ktb * 64 + sk;
  const u16* bG = Bw + (size_t)(bn + srow) * ldb + (size_t)ktb * 64 + sk;
  const size_t aS = (size_t)128 * lda, bS = (size_t)128 * ldb;

  // frag read bases (u16 index inside one [8192] region)
  const int xsw = ((quad ^ ((l16 >> 1) & 3)) << 3);
  const int aBase = (wm * 128 + l16) * 32 + xsw;
  const int bBase = (wn * 64 + l16) * 32 + xsw;

  auto stA = [&](int buf, int kh, int kt) {
    const u16* g = aG + kt * 64 + kh * 32;
    u16* d = (u16*)&lds[buf][0][kh][wave * 512];
    gld_lds16(d, g);
    gld_lds16(d + 4096, g + aS);
  };
  auto stB = [&](int buf, int kh, int kt) {
    const u16* g = bG + kt * 64 + kh * 32;
    u16* d = (u16*)&lds[buf][1][kh][wave * 512];
    gld_lds16(d, g);
    gld_lds16(d + 4096, g + bS);
  };

  f32x4 acc[8][4] = {};
  short8 af_[4], bf_[4];

  // prologue: kt0 all 4 halves -> buf0 ; kt1 k0 halves -> buf1; drain.
  stA(0, 0, 0); stB(0, 0, 0); stA(0, 1, 0); stB(0, 1, 0);
  stA(1, 0, 1); stB(1, 0, 1);
  VMCNT(0);
  __builtin_amdgcn_s_barrier();

  for (int J = 0; J < nIter - 1; ++J) {
    const int o = 2 * J + 1, e = 2 * J + 2, on = 2 * J + 3;
    G256_PHASE(0, 0, 0, 1, stA(1, 1, o),  NOOPST)
    G256_PHASE(0, 0, 1, 0, stB(1, 1, o),  VMCNT(8))
    G256_PHASE(0, 1, 0, 1, stA(0, 0, e),  NOOPST)
    G256_PHASE(0, 1, 1, 0, stB(0, 0, e),  VMCNT(8))
    G256_PHASE(1, 0, 0, 1, stA(0, 1, e),  NOOPST)
    G256_PHASE(1, 0, 1, 0, stB(0, 1, e),  VMCNT(8))
    G256_PHASE(1, 1, 0, 1, stA(1, 0, on), NOOPST)
    G256_PHASE(1, 1, 1, 0, stB(1, 0, on), VMCNT(8))
  }
  {  // peeled last iteration: only O.k1 still needs staging; drain 8->4->0
    const int o = nkt - 1;
    G256_PHASE(0, 0, 0, 1, stA(1, 1, o), NOOPST)
    G256_PHASE(0, 0, 1, 0, stB(1, 1, o), NOOPST)
    G256_PHASE(0, 1, 0, 1, NOOPST,       NOOPST)
    G256_PHASE(0, 1, 1, 0, NOOPST,       VMCNT(4))
    G256_PHASE(1, 0, 0, 1, NOOPST,       NOOPST)
    G256_PHASE(1, 0, 1, 0, NOOPST,       VMCNT(0))
    G256_PHASE(1, 1, 0, 1, NOOPST,       NOOPST)
    G256_PHASE(1, 1, 1, 0, NOOPST,       NOOPST)
  }

  const int m0 = bm + wm * 128 + quad * 4;
  const int n0 = bn + wn * 64 + l16;

  if constexpr (MODE == 0) {
    const int seg = bn >> 10;  // tile never straddles a 1024 segment
    const float* bs = seg == 0 ? bias0 : (seg == 1 ? bias1 : bias2);
    u16* dst = seg == 0 ? ob0 : (seg == 1 ? ob1 : ob2);
    const float sc = seg == 0 ? 0.125f : 1.0f;
    const int nb = (bn & 1023) + wn * 64 + l16;
    #pragma unroll
    for (int a = 0; a < 8; ++a)
      #pragma unroll
      for (int ni = 0; ni < 4; ++ni) {
        int nn = nb + ni * 16;
        float bv = bs[nn];
        #pragma unroll
        for (int r = 0; r < 4; ++r) {
          int m = m0 + a * 16 + r;
          dst[(size_t)m * 1024 + nn] = f2bf((acc[a][ni][r] + bv) * sc);
        }
      }
  } else if constexpr (MODE == 2) {
    #pragma unroll
    for (int a = 0; a < 8; ++a)
      #pragma unroll
      for (int ni = 0; ni < 4; ++ni) {
        int nn = n0 + ni * 16;
        float bv = bias0[nn];
        #pragma unroll
        for (int r = 0; r < 4; ++r) {
          int m = m0 + a * 16 + r;
          ob0[(size_t)m * 4352 + nn] = f2bf(gelu_fast(acc[a][ni][r] + bv));
        }
      }
  } else {  // MODE 3: fp32 partials
    float* op = (kz < 2) ? outf + (size_t)kz * 4194304
                         : outf2 + (size_t)(kz - 2) * 4194304;
    #pragma unroll
    for (int a = 0; a < 8; ++a)
      #pragma unroll
      for (int ni = 0; ni < 4; ++ni) {
        int nn = n0 + ni * 16;
        #pragma unroll
        for (int r = 0; r < 4; ++r)
          op[(size_t)(m0 + a * 16 + r) * ldo + nn] = acc[a][ni][r];
      }
  }
}

// ---------- flash attention (conflict-free LDS) ----------
__global__ __launch_bounds__(256) void attn_kernel(
    const u16* __restrict__ qb, const u16* __restrict__ kb, const u16* __restrict__ vt,
    const float* __restrict__ gate, const float* __restrict__ btab,
    u16* __restrict__ ctxb) {
  __shared__ __align__(16) u16 Qs[64 * 64];
  __shared__ __align__(16) u16 Ks[64 * 64];
  __shared__ __align__(16) u16 Vs[64 * 64];
  __shared__ __align__(16) u16 Ps[4][16 * 64];
  __shared__ u16 btl[2048];
  __shared__ float gbuf[64];

  const int tid = threadIdx.x;
  const int lane = tid & 63, wave = tid >> 6;
  const int quad = lane >> 4, l16 = lane & 15;
  const int it0 = blockIdx.x * 64;
  const int bh = blockIdx.y, b = bh >> 4, h = bh & 15;
  const int sr = lane & 15;
  const int skc = (lane >> 4) * 8;

  for (int idx = tid; idx < 2047; idx += 256) btl[idx] = f2bf(btab[h * 2048 + idx]);
  if (tid < 64) gbuf[tid] = gate[(size_t)bh * 1024 + it0 + tid];

  #pragma unroll
  for (int hf = 0; hf < 2; ++hf)
    gld_lds16(&Qs[wave * 1024 + hf * 512],
              &qb[((size_t)(b * 1024 + it0 + wave * 16 + sr)) * 1024 + h * 64 + hf * 32 + skc]);

  f32x4 oacc[4] = {};
  float mrow[4], lrow[4];
  #pragma unroll
  for (int r = 0; r < 4; ++r) { mrow[r] = -1e30f; lrow[r] = 0.f; }

  __syncthreads();

  for (int jt = 0; jt < 16; ++jt) {
    int j0 = jt * 64;
    #pragma unroll
    for (int hf = 0; hf < 2; ++hf) {
      gld_lds16(&Ks[wave * 1024 + hf * 512],
                &kb[((size_t)(b * 1024 + j0 + wave * 16 + sr)) * 1024 + h * 64 + hf * 32 + skc]);
      gld_lds16(&Vs[wave * 1024 + hf * 512],
                &vt[((size_t)(bh * 64 + wave * 16 + sr)) * 1024 + j0 + hf * 32 + skc]);
    }
    __syncthreads();

    f32x4 sacc[4] = {};
    #pragma unroll
    for (int c = 0; c < 2; ++c) {
      short8 aq = *(const short8*)&Qs[wave * 1024 + (c * 4 + quad) * 128 + l16 * 8];
      #pragma unroll
      for (int nt = 0; nt < 4; ++nt) {
        short8 bk8 = *(const short8*)&Ks[nt * 1024 + (c * 4 + quad) * 128 + l16 * 8];
        sacc[nt] = __builtin_amdgcn_mfma_f32_16x16x32_bf16(aq, bk8, sacc[nt], 0, 0, 0);
      }
    }

    float sc[4][4], mt[4];
    #pragma unroll
    for (int r = 0; r < 4; ++r) {
      int i_loc = wave * 16 + quad * 4 + r;
      int i_glob = it0 + i_loc;
      float g = gbuf[i_loc];
      float mx = -1e30f;
      #pragma unroll
      for (int nt = 0; nt < 4; ++nt) {
        int j = j0 + nt * 16 + l16;
        float s = sacc[nt][r] + g * bf2f(btl[j - i_glob + 1023]);
        sc[nt][r] = s;
        mx = fmaxf(mx, s);
      }
      mt[r] = mx;
    }
    #pragma unroll
    for (int m = 1; m < 16; m <<= 1)
      #pragma unroll
      for (int r = 0; r < 4; ++r) mt[r] = fmaxf(mt[r], __shfl_xor(mt[r], m, 64));

    float alpha[4], ls[4];
    #pragma unroll
    for (int r = 0; r < 4; ++r) {
      float mnew = fmaxf(mrow[r], mt[r]);
      alpha[r] = __expf(mrow[r] - mnew);
      mrow[r] = mnew;
      float lsum = 0.f;
      #pragma unroll
      for (int nt = 0; nt < 4; ++nt) {
        float p = __expf(sc[nt][r] - mnew);
        sc[nt][r] = p;
        lsum += p;
      }
      ls[r] = lsum;
    }
    #pragma unroll
    for (int m = 1; m < 16; m <<= 1)
      #pragma unroll
      for (int r = 0; r < 4; ++r) ls[r] += __shfl_xor(ls[r], m, 64);
    #pragma unroll
    for (int r = 0; r < 4; ++r) lrow[r] = lrow[r] * alpha[r] + ls[r];

    #pragma unroll
    for (int nt = 0; nt < 4; ++nt)
      #pragma unroll
      for (int r = 0; r < 4; ++r)
        Ps[wave][(nt * 2 + (l16 >> 3)) * 128 + (quad * 4 + r) * 8 + (l16 & 7)] = f2bf(sc[nt][r]);

    #pragma unroll
    for (int dt = 0; dt < 4; ++dt)
      #pragma unroll
      for (int r = 0; r < 4; ++r) oacc[dt][r] *= alpha[r];

    #pragma unroll
    for (int c = 0; c < 2; ++c) {
      short8 ap = *(const short8*)&Ps[wave][(c * 4 + quad) * 128 + l16 * 8];
      #pragma unroll
      for (int dt = 0; dt < 4; ++dt) {
        short8 bv8 = *(const short8*)&Vs[dt * 1024 + (c * 4 + quad) * 128 + l16 * 8];
        oacc[dt] = __builtin_amdgcn_mfma_f32_16x16x32_bf16(ap, bv8, oacc[dt], 0, 0, 0);
      }
    }
    __syncthreads();
  }

  #pragma unroll
  for (int dt = 0; dt < 4; ++dt)
    #pragma unroll
    for (int r = 0; r < 4; ++r) {
      int i_loc = wave * 16 + quad * 4 + r;
      int d = dt * 16 + l16;
      float o = oacc[dt][r] / lrow[r];
      ctxb[((size_t)(b * 1024 + it0 + i_loc)) * 1024 + h * 64 + d] = f2bf(o);
    }
}

// ---------- fused reduce(+resid+bias) + LayerNorm (NP partials) ----------
template <bool WRITE_BF16, bool TWO_BIAS, int NP>
__global__ __launch_bounds__(256) void redln_kernel(
    const float* __restrict__ p0, const float* __restrict__ p1,
    const float* __restrict__ p2, const float* __restrict__ p3,
    const float* __restrict__ extra, const float* __restrict__ bias,
    const float* __restrict__ bias2,
    const float* __restrict__ g, const float* __restrict__ bta,
    float* __restrict__ outf, u16* __restrict__ outb) {
  __shared__ float red[8];
  int row = blockIdx.x, tid = threadIdx.x;
  int lane = tid & 63, wave = tid >> 6;
  size_t base = (size_t)row * 1024 + tid * 4;
  float4 a = *(const float4*)&p0[base];
  float4 bb = *(const float4*)&p1[base];
  float4 c = *(const float4*)&extra[base];
  float4 d = *(const float4*)&bias[tid * 4];
  float4 v;
  v.x = a.x + bb.x + c.x + d.x;
  v.y = a.y + bb.y + c.y + d.y;
  v.z = a.z + bb.z + c.z + d.z;
  v.w = a.w + bb.w + c.w + d.w;
  if (NP == 4) {
    float4 e2 = *(const float4*)&p2[base];
    float4 e3 = *(const float4*)&p3[base];
    v.x += e2.x + e3.x; v.y += e2.y + e3.y;
    v.z += e2.z + e3.z; v.w += e2.w + e3.w;
  }
  if (TWO_BIAS) {
    float4 d2 = *(const float4*)&bias2[tid * 4];
    v.x += d2.x; v.y += d2.y; v.z += d2.z; v.w += d2.w;
  }
  float s = v.x + v.y + v.z + v.w;
  #pragma unroll
  for (int m = 1; m < 64; m <<= 1) s += __shfl_xor(s, m, 64);
  if (lane == 0) red[wave] = s;
  __syncthreads();
  float mean = (red[0] + red[1] + red[2] + red[3]) * (1.f / 1024.f);
  float d0 = v.x - mean, d1 = v.y - mean, d2 = v.z - mean, d3 = v.w - mean;
  float sq = d0 * d0 + d1 * d1 + d2 * d2 + d3 * d3;
  #pragma unroll
  for (int m = 1; m < 64; m <<= 1) sq += __shfl_xor(sq, m, 64);
  if (lane == 0) red[4 + wave] = sq;
  __syncthreads();
  float var = (red[4] + red[5] + red[6] + red[7]) * (1.f / 1024.f);
  float rstd = rsqrtf(var + 1e-5f);
  float dd[4] = {d0, d1, d2, d3};
  #pragma unroll
  for (int e = 0; e < 4; ++e) {
    int cidx = tid * 4 + e;
    float val = dd[e] * rstd * g[cidx] + bta[cidx];
    outf[(size_t)row * 1024 + cidx] = val;
    if (WRITE_BF16) outb[(size_t)row * 1024 + cidx] = f2bf(val);
  }
}

// ---------- launch ----------
extern "C" void kernel_launch(void* const* d_in, const int* in_sizes, int n_in,
                              void* d_out, int out_size, void* d_ws, size_t ws_size,
                              hipStream_t stream) {
  const float* x    = (const float*)d_in[0];
  const float* Wq   = (const float*)d_in[1];  const float* bq  = (const float*)d_in[2];
  const float* Wk   = (const float*)d_in[3];  const float* bk  = (const float*)d_in[4];
  const float* Wv   = (const float*)d_in[5];  const float* bv  = (const float*)d_in[6];
  const float* Wo   = (const float*)d_in[7];  const float* bo  = (const float*)d_in[8];
  const float* Wg   = (const float*)d_in[9];  const float* bg  = (const float*)d_in[10];
  const float* gc   = (const float*)d_in[11];
  const float* rel  = (const float*)d_in[12];
  const float* ln1g = (const float*)d_in[13]; const float* ln1b = (const float*)d_in[14];
  const float* W1   = (const float*)d_in[15]; const float* b1  = (const float*)d_in[16];
  const float* W2   = (const float*)d_in[17]; const float* b2  = (const float*)d_in[18];
  const float* ln2g = (const float*)d_in[19]; const float* ln2b = (const float*)d_in[20];
  const float* Wad  = (const float*)d_in[21]; const float* bad = (const float*)d_in[22];
  const float* Wau  = (const float*)d_in[23]; const float* bau = (const float*)d_in[24];
  float* out = (float*)d_out;

  char* ws = (char*)d_ws;
  const size_t MB = 1ull << 20;
  const size_t KB = 1ull << 10;
  (void)n_in; (void)in_sizes; (void)out_size;

  // FF2 split-4 needs 4 contiguous fp32 partials (34..98 MB) -> peak ~134 MB.
  // If the workspace is smaller, fall back to the 118 MB map with FF2 split-2.
  const bool big = ws_size >= (135ull << 20);

  u16 *xb, *wqkv, *qb, *kb, *vbp, *vtb, *ctxb, *wob, *w1ad, *w2au, *ffadp, *hb;
  float *gate, *btab, *P0, *P1, *P2, *P3, *hf;
  xb    = (u16*)(ws + 0 * MB);
  wqkv  = (u16*)(ws + 8 * MB);
  ffadp = (u16*)(ws + 0 * MB);
  P0    = (float*)(ws + 34 * MB);
  P1    = (float*)(ws + 50 * MB);
  if (big) {
    P2   = (float*)(ws + 66 * MB);
    P3   = (float*)(ws + 82 * MB);
    qb   = (u16*)(ws + 66 * MB);
    kb   = (u16*)(ws + 74 * MB);
    vbp  = (u16*)(ws + 82 * MB);
    vtb  = (u16*)(ws + 90 * MB);
    hb   = (u16*)(ws + 82 * MB);      // after redln1 (vbp dead); dead before FF2 writes P3
    ctxb = (u16*)(ws + 98 * MB);
    hf   = (float*)(ws + 98 * MB);    // after redln1 (ctxb dead)
    wob  = (u16*)(ws + 114 * MB);
    w1ad = (u16*)(ws + 116 * MB);
    w2au = (u16*)(ws + 125 * MB);
    gate = (float*)(ws + 133 * MB + 512 * KB);
    btab = (float*)(ws + 133 * MB + 768 * KB);
  } else {
    P2   = P0;  P3 = P0;              // unused (split-2)
    qb   = (u16*)(ws + 14 * MB);
    kb   = (u16*)(ws + 22 * MB);
    vbp  = (u16*)(ws + 30 * MB);
    vtb  = (u16*)(ws + 38 * MB);
    gate = (float*)(ws + 46 * MB);
    btab = (float*)(ws + 46 * MB + 256 * KB);
    ctxb = (u16*)(ws + 66 * MB);
    wob  = (u16*)(ws + 74 * MB);
    w1ad = (u16*)(ws + 76 * MB);
    w2au = (u16*)(ws + 85 * MB);
    hf   = (float*)(ws + 94 * MB);
    hb   = (u16*)(ws + 110 * MB);
  }

  auto cvt = [&](const float* src, u16* dst, int n) {
    cvt_bf16<<<(n / 4 + 255) / 256, 256, 0, stream>>>(src, dst, n / 4);
  };
  cvt(x, xb, 4096 * 1024);
  cvt(Wq, wqkv,               1024 * 1024);
  cvt(Wk, wqkv + 1024 * 1024, 1024 * 1024);
  cvt(Wv, wqkv + 2 * 1024 * 1024, 1024 * 1024);
  cvt(Wo, wob, 1024 * 1024);
  cvt(W1, w1ad, 4096 * 1024);
  cvt(Wad, w1ad + 4096 * 1024, 256 * 1024);
  cvt_pad<<<(1024 * 1024 + 255) / 256, 256, 0, stream>>>(W2, w2au, 1024, 4352, 1024 * 1024);
  cvt_pad<<<(64 * 1024 + 255) / 256, 256, 0, stream>>>(Wau, w2au + 4096, 64, 4352, 64 * 1024);

  btab_kernel<<<128, 256, 0, stream>>>(rel, btab);
  gate_kernel<<<16384, 256, 0, stream>>>(x, Wg, bg, gc, gate);

  // QKV: M=4096 N=3072 K=1024, 256^2 8-phase (192 blocks)
  gemm256<0><<<dim3(16, 12, 1), 512, 0, stream>>>(xb, wqkv, 1024, 1024, 16, 16, 1,
      bq, bk, bv, nullptr, nullptr, 0, qb, kb, vbp);
  vtrans_kernel<<<dim3(16, 64), 256, 0, stream>>>(vbp, vtb);
  attn_kernel<<<dim3(16, 64), 256, 0, stream>>>(qb, kb, vtb, gate, btab, ctxb);
  // Wo split-K x2 -> P0,P1 (legacy 128^2, 512 blocks)
  gemm_bt<3><<<dim3(32, 8, 2), 256, 0, stream>>>(ctxb, wob, 1024, 512, 1024, 0,
      nullptr, nullptr, nullptr, P0, nullptr, nullptr, nullptr);
  // reduce + bo + residual(x) + LN1 -> hf/hb
  redln_kernel<true, false, 2><<<4096, 256, 0, stream>>>(P0, P1, P0, P0, x, bo, nullptr,
      ln1g, ln1b, hf, hb);
  // FF1 proper: N=4096 gelu -> ffadp cols 0..4095 (256 blocks exact)
  gemm256<2><<<dim3(16, 16, 1), 512, 0, stream>>>(hb, w1ad, 1024, 1024, 16, 16, 1,
      b1, nullptr, nullptr, nullptr, nullptr, 0, ffadp, nullptr, nullptr);
  // adapter-down: N=256 elu -> ffadp cols 4096..4351 (legacy kernel, bn0=4096)
  gemm_bt<2><<<dim3(32, 2, 1), 256, 0, stream>>>(hb, w1ad + 4096 * 1024, 1024, 1024, 4352,
      4096, bad, bad, nullptr, nullptr, ffadp, nullptr, nullptr);
  // FF2+adapter-up via K-concat: K=4352
  if (big) {
    // split-K x4 ({18,18,16,16} K-tiles) -> P0..P3, 256 blocks
    gemm256<3><<<dim3(16, 4, 4), 512, 0, stream>>>(ffadp, w2au, 4352, 4352, 18, 16, 2,
        nullptr, nullptr, nullptr, P0, P2, 1024, nullptr, nullptr, nullptr);
    redln_kernel<false, true, 4><<<4096, 256, 0, stream>>>(P0, P1, P2, P3, hf, b2, bau,
        ln2g, ln2b, out, nullptr);
  } else {
    // split-K x2 -> P0,P1, 128 blocks
    gemm256<3><<<dim3(16, 4, 2), 512, 0, stream>>>(ffadp, w2au, 4352, 4352, 34, 34, 2,
        nullptr, nullptr, nullptr, P0, P2, 1024, nullptr, nullptr, nullptr);
    redln_kernel<false, true, 2><<<4096, 256, 0, stream>>>(P0, P1, P0, P0, hf, b2, bau,
        ln2g, ln2b, out, nullptr);
  }
}

// Round 2
// 536.806 us; speedup vs baseline: 1.0224x; 1.0224x over previous
//
#include <hip/hip_runtime.h>
#include <cmath>

typedef unsigned short u16;
using short8 = __attribute__((ext_vector_type(8))) short;   // 8 x bf16
using f32x4  = __attribute__((ext_vector_type(4))) float;   // MFMA acc

// ---------- helpers ----------
__device__ __forceinline__ u16 f2bf(float f) {  // fp32 -> bf16 RNE
  union { float f; unsigned u; } c; c.f = f;
  unsigned r = c.u + 0x7fffu + ((c.u >> 16) & 1u);
  return (u16)(r >> 16);
}
__device__ __forceinline__ float bf2f(u16 b) {
  union { unsigned u; float f; } c; c.u = ((unsigned)b) << 16;
  return c.f;
}

__device__ __forceinline__ void gld_lds16(void* lds, const void* g) {
  __builtin_amdgcn_global_load_lds(
      (const __attribute__((address_space(1))) void*)g,
      (__attribute__((address_space(3))) void*)lds, 16, 0, 0);
}

// fast GELU (tanh approx, max err ~1e-3 << bf16 threshold)
__device__ __forceinline__ float gelu_fast(float t) {
  float u = 0.7978845608f * t * (1.f + 0.044715f * t * t);
  float th = 1.f - 2.f / (__expf(2.f * u) + 1.f);
  return 0.5f * t * (1.f + th);
}

// ---------- fp32 -> bf16 convert ----------
__global__ __launch_bounds__(256) void cvt_bf16(const float* __restrict__ in,
                                                u16* __restrict__ out, int n4) {
  int i = blockIdx.x * 256 + threadIdx.x;
  if (i >= n4) return;
  float4 v = ((const float4*)in)[i];
  ushort4 o;
  o.x = f2bf(v.x); o.y = f2bf(v.y); o.z = f2bf(v.z); o.w = f2bf(v.w);
  ((ushort4*)out)[i] = o;
}

// fp32 -> bf16 into strided (padded) rows
__global__ __launch_bounds__(256) void cvt_pad(const float* __restrict__ in,
                                               u16* __restrict__ out,
                                               int incols4, int outstride, int n4) {
  int i = blockIdx.x * 256 + threadIdx.x;
  if (i >= n4) return;
  int row = i / incols4, c = i - row * incols4;
  float4 v = ((const float4*)in)[i];
  ushort4 o;
  o.x = f2bf(v.x); o.y = f2bf(v.y); o.z = f2bf(v.z); o.w = f2bf(v.w);
  *(ushort4*)&out[(size_t)row * outstride + c * 4] = o;
}

// ---------- relative-position bias table ----------
__global__ __launch_bounds__(256) void btab_kernel(const float* __restrict__ rel_embed,
                                                   float* __restrict__ btab) {
  int idx = blockIdx.x * 256 + threadIdx.x;
  if (idx >= 16 * 2048) return;
  int h = idx >> 11;
  int d = idx & 2047;
  if (d >= 2047) return;
  int rel = d - 1023;
  int bucket = (rel > 0) ? 160 : 0;
  int ar = rel < 0 ? -rel : rel;
  if (ar < 80) {
    bucket += ar;
  } else {
    int large = 80 + (int)(logf((float)ar / 80.0f) / 2.3025851f * 80.0f);
    if (large > 159) large = 159;
    bucket += large;
  }
  btab[h * 2048 + d] = rel_embed[bucket * 16 + h];
}

// ---------- gate ----------
__global__ __launch_bounds__(256) void gate_kernel(const float* __restrict__ x,
                                                   const float* __restrict__ Wg,
                                                   const float* __restrict__ bg,
                                                   const float* __restrict__ gc,
                                                   float* __restrict__ gate_out) {
  int gw = blockIdx.x * 4 + (threadIdx.x >> 6);
  int lane = threadIdx.x & 63;
  int s = gw & 1023, bh = gw >> 10, b = bh >> 4, h = bh & 15;
  float wA = Wg[lane] + Wg[64 + lane] + Wg[128 + lane] + Wg[192 + lane];
  float wB = Wg[256 + lane] + Wg[320 + lane] + Wg[384 + lane] + Wg[448 + lane];
  float xv = x[((size_t)(b * 1024 + s)) * 1024 + h * 64 + lane];
  float pa = xv * wA, pb = xv * wB;
  #pragma unroll
  for (int m = 1; m < 64; m <<= 1) {
    pa += __shfl_xor(pa, m, 64);
    pb += __shfl_xor(pb, m, 64);
  }
  if (lane == 0) {
    float bgA = bg[0] + bg[1] + bg[2] + bg[3];
    float bgB = bg[4] + bg[5] + bg[6] + bg[7];
    float ga = 1.f / (1.f + expf(-(pa + bgA)));
    float gb = 1.f / (1.f + expf(-(pb + bgB)));
    gate_out[(size_t)bh * 1024 + s] = ga * (gb * gc[h] - 1.f) + 2.f;
  }
}

// ---------- V transpose: vt[bh][d][s] ----------
__global__ __launch_bounds__(256) void vtrans_kernel(const u16* __restrict__ vb,
                                                     u16* __restrict__ vt) {
  __shared__ u16 tile[64 * 65];
  int bh = blockIdx.y, b = bh >> 4, h = bh & 15;
  int s0 = blockIdx.x * 64;
  int tid = threadIdx.x;
  int r = tid >> 3, c = (tid & 7) * 8;
  #pragma unroll
  for (int p = 0; p < 2; ++p) {
    int s = p * 32 + r;
    uint4 vv = *(const uint4*)&vb[((size_t)(b * 1024 + s0 + s)) * 1024 + h * 64 + c];
    const u16* pv = (const u16*)&vv;
    #pragma unroll
    for (int e = 0; e < 8; ++e) tile[(c + e) * 65 + s] = pv[e];
  }
  __syncthreads();
  int d = tid & 63, jc0 = tid >> 6;
  #pragma unroll
  for (int jc = jc0; jc < 8; jc += 4) {
    u16 tmp[8];
    #pragma unroll
    for (int e = 0; e < 8; ++e) tmp[e] = tile[d * 65 + jc * 8 + e];
    *(uint4*)&vt[((size_t)(bh * 64 + d)) * 1024 + s0 + jc * 8] = *(uint4*)tmp;
  }
}

// ---------- GEMM 128x128 (legacy 3-stage) — used for Wo split-K ----------
template <int MODE>
__global__ __launch_bounds__(256, 3) void gemm_bt(
    const u16* __restrict__ A, const u16* __restrict__ Bw,
    int K, int Ksub, int N, int bn0,
    const float* __restrict__ bias0, const float* __restrict__ bias1,
    const float* __restrict__ bias2,
    float* __restrict__ outf,
    u16* __restrict__ ob0, u16* __restrict__ ob1, u16* __restrict__ ob2) {
  __shared__ __align__(16) u16 As[3][128 * 32];
  __shared__ __align__(16) u16 Bs[3][128 * 32];
  const int tid = threadIdx.x;
  const int lane = tid & 63, wave = tid >> 6;
  const int quad = lane >> 4, l16 = lane & 15;
  const int bm = blockIdx.x * 128, bn = blockIdx.y * 128;
  const int kz = blockIdx.z;
  const int nsteps = Ksub >> 5;
  const int wm = (wave & 1) * 64, wn = (wave >> 1) * 64;
  const int sr = lane & 15, skc = (lane >> 4) * 8;

  const u16* a0 = A + (size_t)(bm + wave * 32 + sr) * K + kz * Ksub + skc;
  const u16* b0 = Bw + (size_t)(bn + wave * 32 + sr) * K + kz * Ksub + skc;
  const size_t ra = (size_t)16 * K;

  f32x4 acc[4][4] = {};

  #pragma unroll
  for (int t = 0; t < 2; ++t) {
    gld_lds16(&As[0][(wave * 2 + t) * 512], a0 + t * ra);
    gld_lds16(&Bs[0][(wave * 2 + t) * 512], b0 + t * ra);
  }
  if (nsteps > 1) {
    #pragma unroll
    for (int t = 0; t < 2; ++t) {
      gld_lds16(&As[1][(wave * 2 + t) * 512], a0 + t * ra + 32);
      gld_lds16(&Bs[1][(wave * 2 + t) * 512], b0 + t * ra + 32);
    }
  }

  int cur = 0, nxt2 = 2;
  for (int ks = 0; ks < nsteps; ++ks) {
    if (ks + 1 < nsteps) asm volatile("s_waitcnt vmcnt(4)" ::: "memory");
    else                 asm volatile("s_waitcnt vmcnt(0)" ::: "memory");
    __builtin_amdgcn_s_barrier();
    if (ks + 2 < nsteps) {
      int ko = (ks + 2) * 32;
      #pragma unroll
      for (int t = 0; t < 2; ++t) {
        gld_lds16(&As[nxt2][(wave * 2 + t) * 512], a0 + t * ra + ko);
        gld_lds16(&Bs[nxt2][(wave * 2 + t) * 512], b0 + t * ra + ko);
      }
    }
    const u16* Ap = As[cur];
    const u16* Bp = Bs[cur];
    short8 af[4], bf[4];
    #pragma unroll
    for (int mi = 0; mi < 4; ++mi)
      af[mi] = *(const short8*)&Ap[((wm >> 4) + mi) * 512 + quad * 128 + l16 * 8];
    #pragma unroll
    for (int ni = 0; ni < 4; ++ni)
      bf[ni] = *(const short8*)&Bp[((wn >> 4) + ni) * 512 + quad * 128 + l16 * 8];
    #pragma unroll
    for (int mi = 0; mi < 4; ++mi)
      #pragma unroll
      for (int ni = 0; ni < 4; ++ni)
        acc[mi][ni] = __builtin_amdgcn_mfma_f32_16x16x32_bf16(af[mi], bf[ni], acc[mi][ni], 0, 0, 0);
    cur = (cur == 2) ? 0 : cur + 1;
    nxt2 = (nxt2 == 2) ? 0 : nxt2 + 1;
  }

  float* outp = outf + (size_t)kz * 4194304;

  #pragma unroll
  for (int mi = 0; mi < 4; ++mi) {
    #pragma unroll
    for (int ni = 0; ni < 4; ++ni) {
      int col = bn + bn0 + wn + ni * 16 + l16;
      #pragma unroll
      for (int r = 0; r < 4; ++r) {
        int m = bm + wm + mi * 16 + quad * 4 + r;
        float v = acc[mi][ni][r];
        if constexpr (MODE == 0) {
          int seg = col >> 10;
          int nloc = col & 1023;
          const float* bs = seg == 0 ? bias0 : (seg == 1 ? bias1 : bias2);
          u16* dst = seg == 0 ? ob0 : (seg == 1 ? ob1 : ob2);
          v += bs[nloc];
          if (seg == 0) v *= 0.125f;
          dst[(size_t)m * 1024 + nloc] = f2bf(v);
        } else if constexpr (MODE == 2) {
          if (col < 4096) {
            float t = v + bias0[col];
            ob0[(size_t)m * 4352 + col] = f2bf(gelu_fast(t));
          } else {
            float t = v + bias1[col - 4096];
            float e = t > 0.f ? t : (__expf(t) - 1.f);
            ob0[(size_t)m * 4352 + col] = f2bf(e);
          }
        } else {
          outp[(size_t)m * N + col] = v;
        }
      }
    }
  }
}

// ---------- GEMM 256x256, BK=64, 8 waves, 2-phase double-buffer ----------
// Proven-simple structure (T3 minimum 2-phase): per K-tile:
//   issue next-tile stage (8 x global_load_lds) -> ds_read/MFMA current tile
//   (compiler-managed fine-grained lgkmcnt) -> vmcnt(0) (free: ~2.5k cycles of
//   compute since issue) -> one barrier. LDS chunk-XOR swizzle (verified
//   conflict-free in R1 counters): LDS[row][chunk c] holds global chunk
//   c ^ ((row>>1)&3); staging pre-swizzles the per-lane GLOBAL address and
//   keeps the LDS dest linear (rule 21); reads apply the same XOR.
// MODE 0: QKV epilogue (seg bias + q*0.125, bf16 x3)
// MODE 2: FF1 gelu (cols<4096, bias0) / adapter elu (cols>=4096, bias1)
// MODE 3: fp32 partials (split-K x4), 4M-float stride
#define VMCNT(n) asm volatile("s_waitcnt vmcnt(" #n ")" ::: "memory")

#define G256_LDA(BUF, KK, MH)                                               \
  af_[0] = *(const short8*)&lds[BUF][0][KK][aBase + (MH) * 2048 + 0];       \
  af_[1] = *(const short8*)&lds[BUF][0][KK][aBase + (MH) * 2048 + 512];     \
  af_[2] = *(const short8*)&lds[BUF][0][KK][aBase + (MH) * 2048 + 1024];    \
  af_[3] = *(const short8*)&lds[BUF][0][KK][aBase + (MH) * 2048 + 1536];
#define G256_LDB(BUF, KK)                                                   \
  bf_[0] = *(const short8*)&lds[BUF][1][KK][bBase + 0];                     \
  bf_[1] = *(const short8*)&lds[BUF][1][KK][bBase + 512];                   \
  bf_[2] = *(const short8*)&lds[BUF][1][KK][bBase + 1024];                  \
  bf_[3] = *(const short8*)&lds[BUF][1][KK][bBase + 1536];
#define G256_MFMA(MH)                                                       \
  _Pragma("unroll") for (int mi = 0; mi < 4; ++mi)                          \
  _Pragma("unroll") for (int ni = 0; ni < 4; ++ni)                          \
    acc[(MH) * 4 + mi][ni] = __builtin_amdgcn_mfma_f32_16x16x32_bf16(       \
        af_[mi], bf_[ni], acc[(MH) * 4 + mi][ni], 0, 0, 0);
#define G256_TILE(BUF)                                                      \
  G256_LDB(BUF, 0)                                                          \
  G256_LDA(BUF, 0, 0)                                                       \
  G256_MFMA(0)                                                              \
  G256_LDA(BUF, 0, 1)                                                       \
  G256_MFMA(1)                                                              \
  G256_LDB(BUF, 1)                                                          \
  G256_LDA(BUF, 1, 0)                                                       \
  G256_MFMA(0)                                                              \
  G256_LDA(BUF, 1, 1)                                                       \
  G256_MFMA(1)

template <int MODE>
__global__ __launch_bounds__(512, 2) void gemm256(
    const u16* __restrict__ A, const u16* __restrict__ Bw,
    int lda, int ldb, int kt_hi, int kt_lo, int z_hi,
    const float* __restrict__ bias0, const float* __restrict__ bias1,
    const float* __restrict__ bias2,
    float* __restrict__ outf, float* __restrict__ outf2, int ldo,
    u16* __restrict__ ob0, u16* __restrict__ ob1, u16* __restrict__ ob2) {
  __shared__ __align__(16) u16 lds[2][2][2][8192];

  const int tid = threadIdx.x;
  const int lane = tid & 63, wave = tid >> 6;
  const int quad = lane >> 4, l16 = lane & 15;
  const int wm = wave >> 2, wn = wave & 3;

  // XCD-aware bijective swizzle (all grids are multiples of 8 blocks)
  const int gx = gridDim.x, gy = gridDim.y;
  int flat = blockIdx.x + gx * (blockIdx.y + gy * blockIdx.z);
  const int cpx = (gx * gy * gridDim.z) >> 3;
  flat = (flat & 7) * cpx + (flat >> 3);
  const int bmi = flat % gx;
  int rest = flat / gx;
  const int bni = rest % gy;
  const int kz = rest / gy;

  const int bm = bmi * 256, bn = bni * 256;
  const int nkt = (kz < z_hi) ? kt_hi : kt_lo;   // must be EVEN
  const int ktb = (kz < z_hi) ? kz * kt_hi : z_hi * kt_hi + (kz - z_hi) * kt_lo;

  // staging geometry: lane l stages row (wave*16 + l/4) (+128 for 2nd load),
  // global 16B chunk (l&3)^((row>>1)&3) -> linear LDS dest.
  const int srow = wave * 16 + (lane >> 2);
  const int sk = (((lane & 3) ^ ((lane >> 3) & 3)) << 3);
  const u16* aG = A + (size_t)(bm + srow) * lda + (size_t)ktb * 64 + sk;
  const u16* bG = Bw + (size_t)(bn + srow) * ldb + (size_t)ktb * 64 + sk;
  const size_t aS = (size_t)128 * lda, bS = (size_t)128 * ldb;

  // frag read bases (u16 index inside one [8192] region)
  const int xsw = ((quad ^ ((l16 >> 1) & 3)) << 3);
  const int aBase = (wm * 128 + l16) * 32 + xsw;
  const int bBase = (wn * 64 + l16) * 32 + xsw;

  auto stA = [&](int buf, int kh, int kt) {
    const u16* g = aG + kt * 64 + kh * 32;
    u16* d = (u16*)&lds[buf][0][kh][wave * 512];
    gld_lds16(d, g);
    gld_lds16(d + 4096, g + aS);
  };
  auto stB = [&](int buf, int kh, int kt) {
    const u16* g = bG + kt * 64 + kh * 32;
    u16* d = (u16*)&lds[buf][1][kh][wave * 512];
    gld_lds16(d, g);
    gld_lds16(d + 4096, g + bS);
  };

  f32x4 acc[8][4] = {};
  short8 af_[4], bf_[4];

  // prologue: stage tile 0 -> buf0, drain, barrier
  stA(0, 0, 0); stB(0, 0, 0); stA(0, 1, 0); stB(0, 1, 0);
  VMCNT(0);
  __builtin_amdgcn_s_barrier();

  for (int J = 0; J < (nkt >> 1); ++J) {
    {  // even tile t=2J in buf0; prefetch t+1 -> buf1 (always exists)
      const int t1 = 2 * J + 1;
      stA(1, 0, t1); stB(1, 0, t1); stA(1, 1, t1); stB(1, 1, t1);
      G256_TILE(0)
      VMCNT(0);
      __builtin_amdgcn_s_barrier();
    }
    {  // odd tile t=2J+1 in buf1; prefetch t+2 -> buf0 (if exists)
      const int t2 = 2 * J + 2;
      if (t2 < nkt) { stA(0, 0, t2); stB(0, 0, t2); stA(0, 1, t2); stB(0, 1, t2); }
      G256_TILE(1)
      VMCNT(0);
      __builtin_amdgcn_s_barrier();
    }
  }

  const int m0 = bm + wm * 128 + quad * 4;
  const int n0 = bn + wn * 64 + l16;

  if constexpr (MODE == 0) {
    const int seg = bn >> 10;  // tile never straddles a 1024 segment
    const float* bs = seg == 0 ? bias0 : (seg == 1 ? bias1 : bias2);
    u16* dst = seg == 0 ? ob0 : (seg == 1 ? ob1 : ob2);
    const float sc = seg == 0 ? 0.125f : 1.0f;
    const int nb = (bn & 1023) + wn * 64 + l16;
    #pragma unroll
    for (int a = 0; a < 8; ++a)
      #pragma unroll
      for (int ni = 0; ni < 4; ++ni) {
        int nn = nb + ni * 16;
        float bv = bs[nn];
        #pragma unroll
        for (int r = 0; r < 4; ++r) {
          int m = m0 + a * 16 + r;
          dst[(size_t)m * 1024 + nn] = f2bf((acc[a][ni][r] + bv) * sc);
        }
      }
  } else if constexpr (MODE == 2) {
    const bool is_gelu = (bn < 4096);   // block-uniform
    #pragma unroll
    for (int a = 0; a < 8; ++a)
      #pragma unroll
      for (int ni = 0; ni < 4; ++ni) {
        int nn = n0 + ni * 16;
        float bv = is_gelu ? bias0[nn] : bias1[nn - 4096];
        #pragma unroll
        for (int r = 0; r < 4; ++r) {
          int m = m0 + a * 16 + r;
          float t = acc[a][ni][r] + bv;
          float res;
          if (is_gelu) res = gelu_fast(t);
          else         res = t > 0.f ? t : (__expf(t) - 1.f);
          ob0[(size_t)m * 4352 + nn] = f2bf(res);
        }
      }
  } else {  // MODE 3: fp32 partials
    float* op = (kz < 2) ? outf + (size_t)kz * 4194304
                         : outf2 + (size_t)(kz - 2) * 4194304;
    #pragma unroll
    for (int a = 0; a < 8; ++a)
      #pragma unroll
      for (int ni = 0; ni < 4; ++ni) {
        int nn = n0 + ni * 16;
        #pragma unroll
        for (int r = 0; r < 4; ++r)
          op[(size_t)(m0 + a * 16 + r) * ldo + nn] = acc[a][ni][r];
      }
  }
}

// ---------- flash attention: stream K/V from L2, no staging, no jt barriers ----
// K/V per (b,h) is 256KB -> L2-resident; per-lane 16B fragment loads consume
// full 64B sectors (16 rows x 4 quad-chunks per instruction). LDS only holds
// per-wave P staging + bias table + gate (12KB) -> 4 blocks/CU, 16 waves/CU.
__global__ __launch_bounds__(256) void attn_kernel(
    const u16* __restrict__ qb, const u16* __restrict__ kb, const u16* __restrict__ vt,
    const float* __restrict__ gate, const float* __restrict__ btab,
    u16* __restrict__ ctxb) {
  __shared__ __align__(16) u16 Ps[4][16 * 64];
  __shared__ u16 btl[2048];
  __shared__ float gbuf[64];

  const int tid = threadIdx.x;
  const int lane = tid & 63, wave = tid >> 6;
  const int quad = lane >> 4, l16 = lane & 15;
  const int it0 = blockIdx.x * 64;
  const int bh = blockIdx.y, b = bh >> 4, h = bh & 15;

  for (int idx = tid; idx < 2047; idx += 256) btl[idx] = f2bf(btab[h * 2048 + idx]);
  if (tid < 64) gbuf[tid] = gate[(size_t)bh * 1024 + it0 + tid];

  // Q fragments held in registers for the whole kernel
  short8 aq[2];
  #pragma unroll
  for (int c = 0; c < 2; ++c)
    aq[c] = *(const short8*)&qb[((size_t)(b * 1024 + it0 + wave * 16 + l16)) * 1024 +
                                h * 64 + c * 32 + quad * 8];

  f32x4 oacc[4] = {};
  float mrow[4], lrow[4];
  #pragma unroll
  for (int r = 0; r < 4; ++r) { mrow[r] = -1e30f; lrow[r] = 0.f; }

  __syncthreads();   // btl/gbuf ready; the only block-wide barrier

  for (int jt = 0; jt < 16; ++jt) {
    const int j0 = jt * 64;

    // QK^T: stream K fragments from L2
    f32x4 sacc[4] = {};
    #pragma unroll
    for (int c = 0; c < 2; ++c)
      #pragma unroll
      for (int nt = 0; nt < 4; ++nt) {
        short8 bk8 = *(const short8*)&kb[((size_t)(b * 1024 + j0 + nt * 16 + l16)) * 1024 +
                                         h * 64 + c * 32 + quad * 8];
        sacc[nt] = __builtin_amdgcn_mfma_f32_16x16x32_bf16(aq[c], bk8, sacc[nt], 0, 0, 0);
      }

    // hoist V fragment loads: L2 latency overlaps softmax VALU below
    short8 bv[2][4];
    #pragma unroll
    for (int c = 0; c < 2; ++c)
      #pragma unroll
      for (int dt = 0; dt < 4; ++dt)
        bv[c][dt] = *(const short8*)&vt[((size_t)(bh * 64 + dt * 16 + l16)) * 1024 +
                                        j0 + c * 32 + quad * 8];

    float sc[4][4], mt[4];
    #pragma unroll
    for (int r = 0; r < 4; ++r) {
      int i_loc = wave * 16 + quad * 4 + r;
      int i_glob = it0 + i_loc;
      float g = gbuf[i_loc];
      float mx = -1e30f;
      #pragma unroll
      for (int nt = 0; nt < 4; ++nt) {
        int j = j0 + nt * 16 + l16;
        float s = sacc[nt][r] + g * bf2f(btl[j - i_glob + 1023]);
        sc[nt][r] = s;
        mx = fmaxf(mx, s);
      }
      mt[r] = mx;
    }
    #pragma unroll
    for (int m = 1; m < 16; m <<= 1)
      #pragma unroll
      for (int r = 0; r < 4; ++r) mt[r] = fmaxf(mt[r], __shfl_xor(mt[r], m, 64));

    float alpha[4], ls[4];
    #pragma unroll
    for (int r = 0; r < 4; ++r) {
      float mnew = fmaxf(mrow[r], mt[r]);
      alpha[r] = __expf(mrow[r] - mnew);
      mrow[r] = mnew;
      float lsum = 0.f;
      #pragma unroll
      for (int nt = 0; nt < 4; ++nt) {
        float p = __expf(sc[nt][r] - mnew);
        sc[nt][r] = p;
        lsum += p;
      }
      ls[r] = lsum;
    }
    #pragma unroll
    for (int m = 1; m < 16; m <<= 1)
      #pragma unroll
      for (int r = 0; r < 4; ++r) ls[r] += __shfl_xor(ls[r], m, 64);
    #pragma unroll
    for (int r = 0; r < 4; ++r) lrow[r] = lrow[r] * alpha[r] + ls[r];

    // P -> bf16 A-frag repack via per-wave LDS (no barrier: same-wave RAW,
    // compiler inserts lgkmcnt)
    #pragma unroll
    for (int nt = 0; nt < 4; ++nt)
      #pragma unroll
      for (int r = 0; r < 4; ++r)
        Ps[wave][(nt * 2 + (l16 >> 3)) * 128 + (quad * 4 + r) * 8 + (l16 & 7)] = f2bf(sc[nt][r]);

    #pragma unroll
    for (int dt = 0; dt < 4; ++dt)
      #pragma unroll
      for (int r = 0; r < 4; ++r) oacc[dt][r] *= alpha[r];

    #pragma unroll
    for (int c = 0; c < 2; ++c) {
      short8 ap = *(const short8*)&Ps[wave][(c * 4 + quad) * 128 + l16 * 8];
      #pragma unroll
      for (int dt = 0; dt < 4; ++dt)
        oacc[dt] = __builtin_amdgcn_mfma_f32_16x16x32_bf16(ap, bv[c][dt], oacc[dt], 0, 0, 0);
    }
  }

  #pragma unroll
  for (int dt = 0; dt < 4; ++dt)
    #pragma unroll
    for (int r = 0; r < 4; ++r) {
      int i_loc = wave * 16 + quad * 4 + r;
      int d = dt * 16 + l16;
      float o = oacc[dt][r] / lrow[r];
      ctxb[((size_t)(b * 1024 + it0 + i_loc)) * 1024 + h * 64 + d] = f2bf(o);
    }
}

// ---------- fused reduce(+resid+bias) + LayerNorm (NP partials) ----------
template <bool WRITE_BF16, bool TWO_BIAS, int NP>
__global__ __launch_bounds__(256) void redln_kernel(
    const float* __restrict__ p0, const float* __restrict__ p1,
    const float* __restrict__ p2, const float* __restrict__ p3,
    const float* __restrict__ extra, const float* __restrict__ bias,
    const float* __restrict__ bias2,
    const float* __restrict__ g, const float* __restrict__ bta,
    float* __restrict__ outf, u16* __restrict__ outb) {
  __shared__ float red[8];
  int row = blockIdx.x, tid = threadIdx.x;
  int lane = tid & 63, wave = tid >> 6;
  size_t base = (size_t)row * 1024 + tid * 4;
  float4 a = *(const float4*)&p0[base];
  float4 bb = *(const float4*)&p1[base];
  float4 c = *(const float4*)&extra[base];
  float4 d = *(const float4*)&bias[tid * 4];
  float4 v;
  v.x = a.x + bb.x + c.x + d.x;
  v.y = a.y + bb.y + c.y + d.y;
  v.z = a.z + bb.z + c.z + d.z;
  v.w = a.w + bb.w + c.w + d.w;
  if (NP == 4) {
    float4 e2 = *(const float4*)&p2[base];
    float4 e3 = *(const float4*)&p3[base];
    v.x += e2.x + e3.x; v.y += e2.y + e3.y;
    v.z += e2.z + e3.z; v.w += e2.w + e3.w;
  }
  if (TWO_BIAS) {
    float4 d2 = *(const float4*)&bias2[tid * 4];
    v.x += d2.x; v.y += d2.y; v.z += d2.z; v.w += d2.w;
  }
  float s = v.x + v.y + v.z + v.w;
  #pragma unroll
  for (int m = 1; m < 64; m <<= 1) s += __shfl_xor(s, m, 64);
  if (lane == 0) red[wave] = s;
  __syncthreads();
  float mean = (red[0] + red[1] + red[2] + red[3]) * (1.f / 1024.f);
  float d0 = v.x - mean, d1 = v.y - mean, d2 = v.z - mean, d3 = v.w - mean;
  float sq = d0 * d0 + d1 * d1 + d2 * d2 + d3 * d3;
  #pragma unroll
  for (int m = 1; m < 64; m <<= 1) sq += __shfl_xor(sq, m, 64);
  if (lane == 0) red[4 + wave] = sq;
  __syncthreads();
  float var = (red[4] + red[5] + red[6] + red[7]) * (1.f / 1024.f);
  float rstd = rsqrtf(var + 1e-5f);
  float dd[4] = {d0, d1, d2, d3};
  #pragma unroll
  for (int e = 0; e < 4; ++e) {
    int cidx = tid * 4 + e;
    float val = dd[e] * rstd * g[cidx] + bta[cidx];
    outf[(size_t)row * 1024 + cidx] = val;
    if (WRITE_BF16) outb[(size_t)row * 1024 + cidx] = f2bf(val);
  }
}

// ---------- launch ----------
extern "C" void kernel_launch(void* const* d_in, const int* in_sizes, int n_in,
                              void* d_out, int out_size, void* d_ws, size_t ws_size,
                              hipStream_t stream) {
  const float* x    = (const float*)d_in[0];
  const float* Wq   = (const float*)d_in[1];  const float* bq  = (const float*)d_in[2];
  const float* Wk   = (const float*)d_in[3];  const float* bk  = (const float*)d_in[4];
  const float* Wv   = (const float*)d_in[5];  const float* bv  = (const float*)d_in[6];
  const float* Wo   = (const float*)d_in[7];  const float* bo  = (const float*)d_in[8];
  const float* Wg   = (const float*)d_in[9];  const float* bg  = (const float*)d_in[10];
  const float* gc   = (const float*)d_in[11];
  const float* rel  = (const float*)d_in[12];
  const float* ln1g = (const float*)d_in[13]; const float* ln1b = (const float*)d_in[14];
  const float* W1   = (const float*)d_in[15]; const float* b1  = (const float*)d_in[16];
  const float* W2   = (const float*)d_in[17]; const float* b2  = (const float*)d_in[18];
  const float* ln2g = (const float*)d_in[19]; const float* ln2b = (const float*)d_in[20];
  const float* Wad  = (const float*)d_in[21]; const float* bad = (const float*)d_in[22];
  const float* Wau  = (const float*)d_in[23]; const float* bau = (const float*)d_in[24];
  float* out = (float*)d_out;

  char* ws = (char*)d_ws;
  const size_t MB = 1ull << 20;
  const size_t KB = 1ull << 10;
  (void)n_in; (void)in_sizes; (void)out_size;

  const bool big = ws_size >= (135ull << 20);

  u16 *xb, *wqkv, *qb, *kb, *vbp, *vtb, *ctxb, *wob, *w1ad, *w2au, *ffadp, *hb;
  float *gate, *btab, *P0, *P1, *P2, *P3, *hf;
  xb    = (u16*)(ws + 0 * MB);
  wqkv  = (u16*)(ws + 8 * MB);
  ffadp = (u16*)(ws + 0 * MB);
  P0    = (float*)(ws + 34 * MB);
  P1    = (float*)(ws + 50 * MB);
  if (big) {
    P2   = (float*)(ws + 66 * MB);
    P3   = (float*)(ws + 82 * MB);
    qb   = (u16*)(ws + 66 * MB);
    kb   = (u16*)(ws + 74 * MB);
    vbp  = (u16*)(ws + 82 * MB);
    vtb  = (u16*)(ws + 90 * MB);
    hb   = (u16*)(ws + 82 * MB);      // after redln1 (vbp dead); dead before FF2 writes P3
    ctxb = (u16*)(ws + 98 * MB);
    hf   = (float*)(ws + 98 * MB);    // after redln1 (ctxb dead)
    wob  = (u16*)(ws + 114 * MB);
    w1ad = (u16*)(ws + 116 * MB);
    w2au = (u16*)(ws + 125 * MB);
    gate = (float*)(ws + 133 * MB + 512 * KB);
    btab = (float*)(ws + 133 * MB + 768 * KB);
  } else {
    qb   = (u16*)(ws + 14 * MB);
    kb   = (u16*)(ws + 22 * MB);
    vbp  = (u16*)(ws + 30 * MB);
    vtb  = (u16*)(ws + 38 * MB);
    gate = (float*)(ws + 46 * MB);
    btab = (float*)(ws + 46 * MB + 256 * KB);
    ctxb = (u16*)(ws + 66 * MB);
    wob  = (u16*)(ws + 74 * MB);
    w1ad = (u16*)(ws + 76 * MB);
    w2au = (u16*)(ws + 85 * MB);
    hf   = (float*)(ws + 94 * MB);
    hb   = (u16*)(ws + 110 * MB);
    P2   = (float*)(ws + 66 * MB);    // over ctxb (dead at FF2 time)
    P3   = (float*)(ws + 14 * MB);    // over qb/kb (dead at FF2 time)
  }

  auto cvt = [&](const float* src, u16* dst, int n) {
    cvt_bf16<<<(n / 4 + 255) / 256, 256, 0, stream>>>(src, dst, n / 4);
  };
  cvt(x, xb, 4096 * 1024);
  cvt(Wq, wqkv,               1024 * 1024);
  cvt(Wk, wqkv + 1024 * 1024, 1024 * 1024);
  cvt(Wv, wqkv + 2 * 1024 * 1024, 1024 * 1024);
  cvt(Wo, wob, 1024 * 1024);
  cvt(W1, w1ad, 4096 * 1024);
  cvt(Wad, w1ad + 4096 * 1024, 256 * 1024);
  cvt_pad<<<(1024 * 1024 + 255) / 256, 256, 0, stream>>>(W2, w2au, 1024, 4352, 1024 * 1024);
  cvt_pad<<<(64 * 1024 + 255) / 256, 256, 0, stream>>>(Wau, w2au + 4096, 64, 4352, 64 * 1024);

  btab_kernel<<<128, 256, 0, stream>>>(rel, btab);
  gate_kernel<<<16384, 256, 0, stream>>>(x, Wg, bg, gc, gate);

  // QKV: M=4096 N=3072 K=1024 (192 blocks)
  gemm256<0><<<dim3(16, 12, 1), 512, 0, stream>>>(xb, wqkv, 1024, 1024, 16, 16, 1,
      bq, bk, bv, nullptr, nullptr, 0, qb, kb, vbp);
  vtrans_kernel<<<dim3(16, 64), 256, 0, stream>>>(vbp, vtb);
  attn_kernel<<<dim3(16, 64), 256, 0, stream>>>(qb, kb, vtb, gate, btab, ctxb);
  // Wo split-K x2 -> P0,P1 (legacy 128^2, 512 blocks)
  gemm_bt<3><<<dim3(32, 8, 2), 256, 0, stream>>>(ctxb, wob, 1024, 512, 1024, 0,
      nullptr, nullptr, nullptr, P0, nullptr, nullptr, nullptr);
  // reduce + bo + residual(x) + LN1 -> hf/hb
  redln_kernel<true, false, 2><<<4096, 256, 0, stream>>>(P0, P1, P0, P0, x, bo, nullptr,
      ln1g, ln1b, hf, hb);
  // FF1 + adapter-down fused: N=4352 = 17 x 256 (gelu cols<4096, elu cols>=4096)
  gemm256<2><<<dim3(16, 17, 1), 512, 0, stream>>>(hb, w1ad, 1024, 1024, 16, 16, 1,
      b1, bad, nullptr, nullptr, nullptr, 0, ffadp, nullptr, nullptr);
  // FF2+adapter-up via K-concat: K=4352, split-K x4 ({18,18,16,16} K-tiles)
  gemm256<3><<<dim3(16, 4, 4), 512, 0, stream>>>(ffadp, w2au, 4352, 4352, 18, 16, 2,
      nullptr, nullptr, nullptr, P0, P2, 1024, nullptr, nullptr, nullptr);
  redln_kernel<false, true, 4><<<4096, 256, 0, stream>>>(P0, P1, P2, P3, hf, b2, bau,
      ln2g, ln2b, out, nullptr);
}

// Round 3
// 531.456 us; speedup vs baseline: 1.0327x; 1.0101x over previous
//
#include <hip/hip_runtime.h>
#include <cmath>

typedef unsigned short u16;
using short8 = __attribute__((ext_vector_type(8))) short;   // 8 x bf16
using f32x4  = __attribute__((ext_vector_type(4))) float;   // MFMA acc

// ---------- helpers ----------
__device__ __forceinline__ u16 f2bf(float f) {  // fp32 -> bf16 RNE
  union { float f; unsigned u; } c; c.f = f;
  unsigned r = c.u + 0x7fffu + ((c.u >> 16) & 1u);
  return (u16)(r >> 16);
}
__device__ __forceinline__ float bf2f(u16 b) {
  union { unsigned u; float f; } c; c.u = ((unsigned)b) << 16;
  return c.f;
}

__device__ __forceinline__ void gld_lds16(void* lds, const void* g) {
  __builtin_amdgcn_global_load_lds(
      (const __attribute__((address_space(1))) void*)g,
      (__attribute__((address_space(3))) void*)lds, 16, 0, 0);
}

// fast GELU (tanh approx, max err ~1e-3 << bf16 threshold)
__device__ __forceinline__ float gelu_fast(float t) {
  float u = 0.7978845608f * t * (1.f + 0.044715f * t * t);
  float th = 1.f - 2.f / (__expf(2.f * u) + 1.f);
  return 0.5f * t * (1.f + th);
}

// ---------- fp32 -> bf16 convert ----------
__global__ __launch_bounds__(256) void cvt_bf16(const float* __restrict__ in,
                                                u16* __restrict__ out, int n4) {
  int i = blockIdx.x * 256 + threadIdx.x;
  if (i >= n4) return;
  float4 v = ((const float4*)in)[i];
  ushort4 o;
  o.x = f2bf(v.x); o.y = f2bf(v.y); o.z = f2bf(v.z); o.w = f2bf(v.w);
  ((ushort4*)out)[i] = o;
}

// fp32 -> bf16 into strided (padded) rows
__global__ __launch_bounds__(256) void cvt_pad(const float* __restrict__ in,
                                               u16* __restrict__ out,
                                               int incols4, int outstride, int n4) {
  int i = blockIdx.x * 256 + threadIdx.x;
  if (i >= n4) return;
  int row = i / incols4, c = i - row * incols4;
  float4 v = ((const float4*)in)[i];
  ushort4 o;
  o.x = f2bf(v.x); o.y = f2bf(v.y); o.z = f2bf(v.z); o.w = f2bf(v.w);
  *(ushort4*)&out[(size_t)row * outstride + c * 4] = o;
}

// ---------- relative-position bias table ----------
__global__ __launch_bounds__(256) void btab_kernel(const float* __restrict__ rel_embed,
                                                   float* __restrict__ btab) {
  int idx = blockIdx.x * 256 + threadIdx.x;
  if (idx >= 16 * 2048) return;
  int h = idx >> 11;
  int d = idx & 2047;
  if (d >= 2047) return;
  int rel = d - 1023;
  int bucket = (rel > 0) ? 160 : 0;
  int ar = rel < 0 ? -rel : rel;
  if (ar < 80) {
    bucket += ar;
  } else {
    int large = 80 + (int)(logf((float)ar / 80.0f) / 2.3025851f * 80.0f);
    if (large > 159) large = 159;
    bucket += large;
  }
  btab[h * 2048 + d] = rel_embed[bucket * 16 + h];
}

// ---------- gate ----------
__global__ __launch_bounds__(256) void gate_kernel(const float* __restrict__ x,
                                                   const float* __restrict__ Wg,
                                                   const float* __restrict__ bg,
                                                   const float* __restrict__ gc,
                                                   float* __restrict__ gate_out) {
  int gw = blockIdx.x * 4 + (threadIdx.x >> 6);
  int lane = threadIdx.x & 63;
  int s = gw & 1023, bh = gw >> 10, b = bh >> 4, h = bh & 15;
  float wA = Wg[lane] + Wg[64 + lane] + Wg[128 + lane] + Wg[192 + lane];
  float wB = Wg[256 + lane] + Wg[320 + lane] + Wg[384 + lane] + Wg[448 + lane];
  float xv = x[((size_t)(b * 1024 + s)) * 1024 + h * 64 + lane];
  float pa = xv * wA, pb = xv * wB;
  #pragma unroll
  for (int m = 1; m < 64; m <<= 1) {
    pa += __shfl_xor(pa, m, 64);
    pb += __shfl_xor(pb, m, 64);
  }
  if (lane == 0) {
    float bgA = bg[0] + bg[1] + bg[2] + bg[3];
    float bgB = bg[4] + bg[5] + bg[6] + bg[7];
    float ga = 1.f / (1.f + expf(-(pa + bgA)));
    float gb = 1.f / (1.f + expf(-(pb + bgB)));
    gate_out[(size_t)bh * 1024 + s] = ga * (gb * gc[h] - 1.f) + 2.f;
  }
}

// ---------- V transpose: vt[bh][d][s] ----------
__global__ __launch_bounds__(256) void vtrans_kernel(const u16* __restrict__ vb,
                                                     u16* __restrict__ vt) {
  __shared__ u16 tile[64 * 65];
  int bh = blockIdx.y, b = bh >> 4, h = bh & 15;
  int s0 = blockIdx.x * 64;
  int tid = threadIdx.x;
  int r = tid >> 3, c = (tid & 7) * 8;
  #pragma unroll
  for (int p = 0; p < 2; ++p) {
    int s = p * 32 + r;
    uint4 vv = *(const uint4*)&vb[((size_t)(b * 1024 + s0 + s)) * 1024 + h * 64 + c];
    const u16* pv = (const u16*)&vv;
    #pragma unroll
    for (int e = 0; e < 8; ++e) tile[(c + e) * 65 + s] = pv[e];
  }
  __syncthreads();
  int d = tid & 63, jc0 = tid >> 6;
  #pragma unroll
  for (int jc = jc0; jc < 8; jc += 4) {
    u16 tmp[8];
    #pragma unroll
    for (int e = 0; e < 8; ++e) tmp[e] = tile[d * 65 + jc * 8 + e];
    *(uint4*)&vt[((size_t)(bh * 64 + d)) * 1024 + s0 + jc * 8] = *(uint4*)tmp;
  }
}

// ---------- GEMM 256x256, BK=64, 8 waves, 2-phase double-buffer ----------
// Per K-tile: issue next-tile stage (8 x global_load_lds) -> ds_read/MFMA
// current tile (compiler-managed lgkmcnt) -> vmcnt(0) (covered by ~2.5k cycles
// of MFMA since issue) -> one barrier. LDS chunk-XOR swizzle, staging
// pre-swizzles the per-lane GLOBAL address, LDS dest stays linear (rule 21).
// MODE 0: QKV epilogue (seg bias + q*0.125, bf16 x3)
// MODE 2: FF1 gelu (cols<4096, bias0) / adapter elu (cols>=4096, bias1)
// MODE 3: fp32 partials (split-K x4), 4M-float stride, P0|P1 contiguous,
//         kz=2 -> outf2, kz=3 -> outf3
#define VMCNT(n) asm volatile("s_waitcnt vmcnt(" #n ")" ::: "memory")

#define G256_LDA(BUF, KK, MH)                                               \
  af_[0] = *(const short8*)&lds[BUF][0][KK][aBase + (MH) * 2048 + 0];       \
  af_[1] = *(const short8*)&lds[BUF][0][KK][aBase + (MH) * 2048 + 512];     \
  af_[2] = *(const short8*)&lds[BUF][0][KK][aBase + (MH) * 2048 + 1024];    \
  af_[3] = *(const short8*)&lds[BUF][0][KK][aBase + (MH) * 2048 + 1536];
#define G256_LDB(BUF, KK)                                                   \
  bf_[0] = *(const short8*)&lds[BUF][1][KK][bBase + 0];                     \
  bf_[1] = *(const short8*)&lds[BUF][1][KK][bBase + 512];                   \
  bf_[2] = *(const short8*)&lds[BUF][1][KK][bBase + 1024];                  \
  bf_[3] = *(const short8*)&lds[BUF][1][KK][bBase + 1536];
#define G256_MFMA(MH)                                                       \
  _Pragma("unroll") for (int mi = 0; mi < 4; ++mi)                          \
  _Pragma("unroll") for (int ni = 0; ni < 4; ++ni)                          \
    acc[(MH) * 4 + mi][ni] = __builtin_amdgcn_mfma_f32_16x16x32_bf16(       \
        af_[mi], bf_[ni], acc[(MH) * 4 + mi][ni], 0, 0, 0);
#define G256_TILE(BUF)                                                      \
  G256_LDB(BUF, 0)                                                          \
  G256_LDA(BUF, 0, 0)                                                       \
  G256_MFMA(0)                                                              \
  G256_LDA(BUF, 0, 1)                                                       \
  G256_MFMA(1)                                                              \
  G256_LDB(BUF, 1)                                                          \
  G256_LDA(BUF, 1, 0)                                                       \
  G256_MFMA(0)                                                              \
  G256_LDA(BUF, 1, 1)                                                       \
  G256_MFMA(1)

template <int MODE>
__global__ __launch_bounds__(512, 2) void gemm256(
    const u16* __restrict__ A, const u16* __restrict__ Bw,
    int lda, int ldb, int kt_hi, int kt_lo, int z_hi,
    const float* __restrict__ bias0, const float* __restrict__ bias1,
    const float* __restrict__ bias2,
    float* __restrict__ outf, float* __restrict__ outf2,
    float* __restrict__ outf3, int ldo,
    u16* __restrict__ ob0, u16* __restrict__ ob1, u16* __restrict__ ob2) {
  __shared__ __align__(16) u16 lds[2][2][2][8192];

  const int tid = threadIdx.x;
  const int lane = tid & 63, wave = tid >> 6;
  const int quad = lane >> 4, l16 = lane & 15;
  const int wm = wave >> 2, wn = wave & 3;

  // XCD-aware bijective swizzle (all grids are multiples of 8 blocks)
  const int gx = gridDim.x, gy = gridDim.y;
  int flat = blockIdx.x + gx * (blockIdx.y + gy * blockIdx.z);
  const int cpx = (gx * gy * gridDim.z) >> 3;
  flat = (flat & 7) * cpx + (flat >> 3);
  const int bmi = flat % gx;
  int rest = flat / gx;
  const int bni = rest % gy;
  const int kz = rest / gy;

  const int bm = bmi * 256, bn = bni * 256;
  const int nkt = (kz < z_hi) ? kt_hi : kt_lo;   // must be EVEN
  const int ktb = (kz < z_hi) ? kz * kt_hi : z_hi * kt_hi + (kz - z_hi) * kt_lo;

  // staging geometry: lane l stages row (wave*16 + l/4) (+128 for 2nd load),
  // global 16B chunk (l&3)^((row>>1)&3) -> linear LDS dest.
  const int srow = wave * 16 + (lane >> 2);
  const int sk = (((lane & 3) ^ ((lane >> 3) & 3)) << 3);
  const u16* aG = A + (size_t)(bm + srow) * lda + (size_t)ktb * 64 + sk;
  const u16* bG = Bw + (size_t)(bn + srow) * ldb + (size_t)ktb * 64 + sk;
  const size_t aS = (size_t)128 * lda, bS = (size_t)128 * ldb;

  // frag read bases (u16 index inside one [8192] region)
  const int xsw = ((quad ^ ((l16 >> 1) & 3)) << 3);
  const int aBase = (wm * 128 + l16) * 32 + xsw;
  const int bBase = (wn * 64 + l16) * 32 + xsw;

  auto stA = [&](int buf, int kh, int kt) {
    const u16* g = aG + kt * 64 + kh * 32;
    u16* d = (u16*)&lds[buf][0][kh][wave * 512];
    gld_lds16(d, g);
    gld_lds16(d + 4096, g + aS);
  };
  auto stB = [&](int buf, int kh, int kt) {
    const u16* g = bG + kt * 64 + kh * 32;
    u16* d = (u16*)&lds[buf][1][kh][wave * 512];
    gld_lds16(d, g);
    gld_lds16(d + 4096, g + bS);
  };

  f32x4 acc[8][4] = {};
  short8 af_[4], bf_[4];

  // prologue: stage tile 0 -> buf0, drain, barrier
  stA(0, 0, 0); stB(0, 0, 0); stA(0, 1, 0); stB(0, 1, 0);
  VMCNT(0);
  __builtin_amdgcn_s_barrier();

  for (int J = 0; J < (nkt >> 1); ++J) {
    {  // even tile t=2J in buf0; prefetch t+1 -> buf1 (always exists)
      const int t1 = 2 * J + 1;
      stA(1, 0, t1); stB(1, 0, t1); stA(1, 1, t1); stB(1, 1, t1);
      G256_TILE(0)
      VMCNT(0);
      __builtin_amdgcn_s_barrier();
    }
    {  // odd tile t=2J+1 in buf1; prefetch t+2 -> buf0 (if exists)
      const int t2 = 2 * J + 2;
      if (t2 < nkt) { stA(0, 0, t2); stB(0, 0, t2); stA(0, 1, t2); stB(0, 1, t2); }
      G256_TILE(1)
      VMCNT(0);
      __builtin_amdgcn_s_barrier();
    }
  }

  const int m0 = bm + wm * 128 + quad * 4;
  const int n0 = bn + wn * 64 + l16;

  if constexpr (MODE == 0) {
    const int seg = bn >> 10;  // tile never straddles a 1024 segment
    const float* bs = seg == 0 ? bias0 : (seg == 1 ? bias1 : bias2);
    u16* dst = seg == 0 ? ob0 : (seg == 1 ? ob1 : ob2);
    const float sc = seg == 0 ? 0.125f : 1.0f;
    const int nb = (bn & 1023) + wn * 64 + l16;
    #pragma unroll
    for (int a = 0; a < 8; ++a)
      #pragma unroll
      for (int ni = 0; ni < 4; ++ni) {
        int nn = nb + ni * 16;
        float bv = bs[nn];
        #pragma unroll
        for (int r = 0; r < 4; ++r) {
          int m = m0 + a * 16 + r;
          dst[(size_t)m * 1024 + nn] = f2bf((acc[a][ni][r] + bv) * sc);
        }
      }
  } else if constexpr (MODE == 2) {
    const bool is_gelu = (bn < 4096);   // block-uniform
    #pragma unroll
    for (int a = 0; a < 8; ++a)
      #pragma unroll
      for (int ni = 0; ni < 4; ++ni) {
        int nn = n0 + ni * 16;
        float bv = is_gelu ? bias0[nn] : bias1[nn - 4096];
        #pragma unroll
        for (int r = 0; r < 4; ++r) {
          int m = m0 + a * 16 + r;
          float t = acc[a][ni][r] + bv;
          float res;
          if (is_gelu) res = gelu_fast(t);
          else         res = t > 0.f ? t : (__expf(t) - 1.f);
          ob0[(size_t)m * 4352 + nn] = f2bf(res);
        }
      }
  } else {  // MODE 3: fp32 partials
    float* op = (kz == 0) ? outf
              : (kz == 1) ? outf + 4194304
              : (kz == 2) ? outf2 : outf3;
    #pragma unroll
    for (int a = 0; a < 8; ++a)
      #pragma unroll
      for (int ni = 0; ni < 4; ++ni) {
        int nn = n0 + ni * 16;
        #pragma unroll
        for (int r = 0; r < 4; ++r)
          op[(size_t)(m0 + a * 16 + r) * ldo + nn] = acc[a][ni][r];
      }
  }
}

// ---------- flash attention: stream K/V from L2, K reg-double-buffered ----------
// grid (bh=64, it0=16): flat%8 = bh%8 -> all 16 blocks of one (b,h) land on
// one XCD; K/V fetched from HBM once per XCD (FETCH ~70MB -> ~30MB).
// K fragments for tile jt+1 are issued at the top of tile jt (full iteration
// of MFMA+softmax ~1500cy covers L2 latency); V hoisted above softmax.
__global__ __launch_bounds__(256, 2) void attn_kernel(
    const u16* __restrict__ qb, const u16* __restrict__ kb, const u16* __restrict__ vt,
    const float* __restrict__ gate, const float* __restrict__ btab,
    u16* __restrict__ ctxb) {
  __shared__ __align__(16) u16 Ps[4][16 * 64];
  __shared__ u16 btl[2048];
  __shared__ float gbuf[64];

  const int tid = threadIdx.x;
  const int lane = tid & 63, wave = tid >> 6;
  const int quad = lane >> 4, l16 = lane & 15;
  const int bh = blockIdx.x, b = bh >> 4, h = bh & 15;
  const int it0 = blockIdx.y * 64;

  for (int idx = tid; idx < 2047; idx += 256) btl[idx] = f2bf(btab[h * 2048 + idx]);
  if (tid < 64) gbuf[tid] = gate[(size_t)bh * 1024 + it0 + tid];

  // Q fragments held in registers for the whole kernel
  short8 aq[2];
  #pragma unroll
  for (int c = 0; c < 2; ++c)
    aq[c] = *(const short8*)&qb[((size_t)(b * 1024 + it0 + wave * 16 + l16)) * 1024 +
                                h * 64 + c * 32 + quad * 8];

  short8 kA[2][4], kB[2][4];
  auto loadK = [&](short8 (&kr)[2][4], int jt) {
    const int j0 = jt * 64;
    #pragma unroll
    for (int c = 0; c < 2; ++c)
      #pragma unroll
      for (int nt = 0; nt < 4; ++nt)
        kr[c][nt] = *(const short8*)&kb[((size_t)(b * 1024 + j0 + nt * 16 + l16)) * 1024 +
                                        h * 64 + c * 32 + quad * 8];
  };
  loadK(kA, 0);

  f32x4 oacc[4] = {};
  float mrow[4], lrow[4];
  #pragma unroll
  for (int r = 0; r < 4; ++r) { mrow[r] = -1e30f; lrow[r] = 0.f; }

  __syncthreads();   // btl/gbuf ready; the only block-wide barrier

  auto body = [&](int jt, short8 (&kc)[2][4], short8 (&kn)[2][4], bool pf) {
    const int j0 = jt * 64;
    if (pf) loadK(kn, jt + 1);    // prefetch next K tile (consumed next iter)

    // QK^T on current (in-register) K tile
    f32x4 sacc[4] = {};
    #pragma unroll
    for (int c = 0; c < 2; ++c)
      #pragma unroll
      for (int nt = 0; nt < 4; ++nt)
        sacc[nt] = __builtin_amdgcn_mfma_f32_16x16x32_bf16(aq[c], kc[c][nt], sacc[nt], 0, 0, 0);

    // hoist V fragment loads: L2 latency overlaps softmax VALU below
    short8 bv[2][4];
    #pragma unroll
    for (int c = 0; c < 2; ++c)
      #pragma unroll
      for (int dt = 0; dt < 4; ++dt)
        bv[c][dt] = *(const short8*)&vt[((size_t)(bh * 64 + dt * 16 + l16)) * 1024 +
                                        j0 + c * 32 + quad * 8];

    float sc[4][4], mt[4];
    #pragma unroll
    for (int r = 0; r < 4; ++r) {
      int i_loc = wave * 16 + quad * 4 + r;
      int i_glob = it0 + i_loc;
      float g = gbuf[i_loc];
      float mx = -1e30f;
      #pragma unroll
      for (int nt = 0; nt < 4; ++nt) {
        int j = j0 + nt * 16 + l16;
        float s = sacc[nt][r] + g * bf2f(btl[j - i_glob + 1023]);
        sc[nt][r] = s;
        mx = fmaxf(mx, s);
      }
      mt[r] = mx;
    }
    #pragma unroll
    for (int m = 1; m < 16; m <<= 1)
      #pragma unroll
      for (int r = 0; r < 4; ++r) mt[r] = fmaxf(mt[r], __shfl_xor(mt[r], m, 64));

    float alpha[4], ls[4];
    #pragma unroll
    for (int r = 0; r < 4; ++r) {
      float mnew = fmaxf(mrow[r], mt[r]);
      alpha[r] = __expf(mrow[r] - mnew);
      mrow[r] = mnew;
      float lsum = 0.f;
      #pragma unroll
      for (int nt = 0; nt < 4; ++nt) {
        float p = __expf(sc[nt][r] - mnew);
        sc[nt][r] = p;
        lsum += p;
      }
      ls[r] = lsum;
    }
    #pragma unroll
    for (int m = 1; m < 16; m <<= 1)
      #pragma unroll
      for (int r = 0; r < 4; ++r) ls[r] += __shfl_xor(ls[r], m, 64);
    #pragma unroll
    for (int r = 0; r < 4; ++r) lrow[r] = lrow[r] * alpha[r] + ls[r];

    // P -> bf16 A-frag repack via per-wave LDS (same-wave RAW, lgkmcnt only)
    #pragma unroll
    for (int nt = 0; nt < 4; ++nt)
      #pragma unroll
      for (int r = 0; r < 4; ++r)
        Ps[wave][(nt * 2 + (l16 >> 3)) * 128 + (quad * 4 + r) * 8 + (l16 & 7)] = f2bf(sc[nt][r]);

    #pragma unroll
    for (int dt = 0; dt < 4; ++dt)
      #pragma unroll
      for (int r = 0; r < 4; ++r) oacc[dt][r] *= alpha[r];

    #pragma unroll
    for (int c = 0; c < 2; ++c) {
      short8 ap = *(const short8*)&Ps[wave][(c * 4 + quad) * 128 + l16 * 8];
      #pragma unroll
      for (int dt = 0; dt < 4; ++dt)
        oacc[dt] = __builtin_amdgcn_mfma_f32_16x16x32_bf16(ap, bv[c][dt], oacc[dt], 0, 0, 0);
    }
  };

  for (int J = 0; J < 8; ++J) {
    body(2 * J,     kA, kB, true);
    body(2 * J + 1, kB, kA, J < 7);
  }

  #pragma unroll
  for (int dt = 0; dt < 4; ++dt)
    #pragma unroll
    for (int r = 0; r < 4; ++r) {
      int i_loc = wave * 16 + quad * 4 + r;
      int d = dt * 16 + l16;
      float o = oacc[dt][r] / lrow[r];
      ctxb[((size_t)(b * 1024 + it0 + i_loc)) * 1024 + h * 64 + d] = f2bf(o);
    }
}

// ---------- fused reduce(+resid+bias) + LayerNorm (NP partials) ----------
template <bool WRITE_BF16, bool TWO_BIAS, int NP>
__global__ __launch_bounds__(256) void redln_kernel(
    const float* __restrict__ p0, const float* __restrict__ p1,
    const float* __restrict__ p2, const float* __restrict__ p3,
    const float* __restrict__ extra, const float* __restrict__ bias,
    const float* __restrict__ bias2,
    const float* __restrict__ g, const float* __restrict__ bta,
    float* __restrict__ outf, u16* __restrict__ outb) {
  __shared__ float red[8];
  int row = blockIdx.x, tid = threadIdx.x;
  int lane = tid & 63, wave = tid >> 6;
  size_t base = (size_t)row * 1024 + tid * 4;
  float4 a = *(const float4*)&p0[base];
  float4 bb = *(const float4*)&p1[base];
  float4 c = *(const float4*)&extra[base];
  float4 d = *(const float4*)&bias[tid * 4];
  float4 v;
  v.x = a.x + bb.x + c.x + d.x;
  v.y = a.y + bb.y + c.y + d.y;
  v.z = a.z + bb.z + c.z + d.z;
  v.w = a.w + bb.w + c.w + d.w;
  if (NP == 4) {
    float4 e2 = *(const float4*)&p2[base];
    float4 e3 = *(const float4*)&p3[base];
    v.x += e2.x + e3.x; v.y += e2.y + e3.y;
    v.z += e2.z + e3.z; v.w += e2.w + e3.w;
  }
  if (TWO_BIAS) {
    float4 d2 = *(const float4*)&bias2[tid * 4];
    v.x += d2.x; v.y += d2.y; v.z += d2.z; v.w += d2.w;
  }
  float s = v.x + v.y + v.z + v.w;
  #pragma unroll
  for (int m = 1; m < 64; m <<= 1) s += __shfl_xor(s, m, 64);
  if (lane == 0) red[wave] = s;
  __syncthreads();
  float mean = (red[0] + red[1] + red[2] + red[3]) * (1.f / 1024.f);
  float d0 = v.x - mean, d1 = v.y - mean, d2 = v.z - mean, d3 = v.w - mean;
  float sq = d0 * d0 + d1 * d1 + d2 * d2 + d3 * d3;
  #pragma unroll
  for (int m = 1; m < 64; m <<= 1) sq += __shfl_xor(sq, m, 64);
  if (lane == 0) red[4 + wave] = sq;
  __syncthreads();
  float var = (red[4] + red[5] + red[6] + red[7]) * (1.f / 1024.f);
  float rstd = rsqrtf(var + 1e-5f);
  float dd[4] = {d0, d1, d2, d3};
  #pragma unroll
  for (int e = 0; e < 4; ++e) {
    int cidx = tid * 4 + e;
    float val = dd[e] * rstd * g[cidx] + bta[cidx];
    outf[(size_t)row * 1024 + cidx] = val;
    if (WRITE_BF16) outb[(size_t)row * 1024 + cidx] = f2bf(val);
  }
}

// ---------- launch ----------
extern "C" void kernel_launch(void* const* d_in, const int* in_sizes, int n_in,
                              void* d_out, int out_size, void* d_ws, size_t ws_size,
                              hipStream_t stream) {
  const float* x    = (const float*)d_in[0];
  const float* Wq   = (const float*)d_in[1];  const float* bq  = (const float*)d_in[2];
  const float* Wk   = (const float*)d_in[3];  const float* bk  = (const float*)d_in[4];
  const float* Wv   = (const float*)d_in[5];  const float* bv  = (const float*)d_in[6];
  const float* Wo   = (const float*)d_in[7];  const float* bo  = (const float*)d_in[8];
  const float* Wg   = (const float*)d_in[9];  const float* bg  = (const float*)d_in[10];
  const float* gc   = (const float*)d_in[11];
  const float* rel  = (const float*)d_in[12];
  const float* ln1g = (const float*)d_in[13]; const float* ln1b = (const float*)d_in[14];
  const float* W1   = (const float*)d_in[15]; const float* b1  = (const float*)d_in[16];
  const float* W2   = (const float*)d_in[17]; const float* b2  = (const float*)d_in[18];
  const float* ln2g = (const float*)d_in[19]; const float* ln2b = (const float*)d_in[20];
  const float* Wad  = (const float*)d_in[21]; const float* bad = (const float*)d_in[22];
  const float* Wau  = (const float*)d_in[23]; const float* bau = (const float*)d_in[24];
  float* out = (float*)d_out;

  char* ws = (char*)d_ws;
  const size_t MB = 1ull << 20;
  const size_t KB = 1ull << 10;
  (void)n_in; (void)in_sizes; (void)out_size;

  const bool big = ws_size >= (135ull << 20);

  u16 *xb, *wqkv, *qb, *kb, *vbp, *vtb, *ctxb, *wob, *w1ad, *w2au, *ffadp, *hb;
  float *gate, *btab, *P0, *P1, *P2, *P3, *hf;
  xb    = (u16*)(ws + 0 * MB);
  wqkv  = (u16*)(ws + 8 * MB);
  ffadp = (u16*)(ws + 0 * MB);
  P0    = (float*)(ws + 34 * MB);
  P1    = (float*)(ws + 50 * MB);
  // Wo split-4 partials kz=2,3 -> ws 0..32MB (xb/wqkv/qb/kb/vbp all dead by Wo)
  float* PW2 = (float*)(ws + 0 * MB);
  float* PW3 = (float*)(ws + 16 * MB);
  if (big) {
    P2   = (float*)(ws + 66 * MB);
    P3   = (float*)(ws + 82 * MB);
    qb   = (u16*)(ws + 66 * MB);
    kb   = (u16*)(ws + 74 * MB);
    vbp  = (u16*)(ws + 82 * MB);
    vtb  = (u16*)(ws + 90 * MB);
    hb   = (u16*)(ws + 82 * MB);      // after redln1 (vbp dead); dead before FF2 writes P3
    ctxb = (u16*)(ws + 98 * MB);
    hf   = (float*)(ws + 98 * MB);    // after redln1 (ctxb dead)
    wob  = (u16*)(ws + 114 * MB);
    w1ad = (u16*)(ws + 116 * MB);
    w2au = (u16*)(ws + 125 * MB);
    gate = (float*)(ws + 133 * MB + 512 * KB);
    btab = (float*)(ws + 133 * MB + 768 * KB);
  } else {
    qb   = (u16*)(ws + 14 * MB);
    kb   = (u16*)(ws + 22 * MB);
    vbp  = (u16*)(ws + 30 * MB);
    vtb  = (u16*)(ws + 38 * MB);
    gate = (float*)(ws + 46 * MB);
    btab = (float*)(ws + 46 * MB + 256 * KB);
    ctxb = (u16*)(ws + 66 * MB);
    wob  = (u16*)(ws + 74 * MB);
    w1ad = (u16*)(ws + 76 * MB);
    w2au = (u16*)(ws + 85 * MB);
    hf   = (float*)(ws + 94 * MB);
    hb   = (u16*)(ws + 110 * MB);
    P2   = (float*)(ws + 66 * MB);    // over ctxb (dead at FF2 time)
    P3   = (float*)(ws + 14 * MB);    // over qb/kb (dead at FF2 time)
  }

  auto cvt = [&](const float* src, u16* dst, int n) {
    cvt_bf16<<<(n / 4 + 255) / 256, 256, 0, stream>>>(src, dst, n / 4);
  };
  cvt(x, xb, 4096 * 1024);
  cvt(Wq, wqkv,               1024 * 1024);
  cvt(Wk, wqkv + 1024 * 1024, 1024 * 1024);
  cvt(Wv, wqkv + 2 * 1024 * 1024, 1024 * 1024);
  cvt(Wo, wob, 1024 * 1024);
  cvt(W1, w1ad, 4096 * 1024);
  cvt(Wad, w1ad + 4096 * 1024, 256 * 1024);
  cvt_pad<<<(1024 * 1024 + 255) / 256, 256, 0, stream>>>(W2, w2au, 1024, 4352, 1024 * 1024);
  cvt_pad<<<(64 * 1024 + 255) / 256, 256, 0, stream>>>(Wau, w2au + 4096, 64, 4352, 64 * 1024);

  btab_kernel<<<128, 256, 0, stream>>>(rel, btab);
  gate_kernel<<<16384, 256, 0, stream>>>(x, Wg, bg, gc, gate);

  // QKV: M=4096 N=3072 K=1024 (192 blocks)
  gemm256<0><<<dim3(16, 12, 1), 512, 0, stream>>>(xb, wqkv, 1024, 1024, 16, 16, 1,
      bq, bk, bv, nullptr, nullptr, nullptr, 0, qb, kb, vbp);
  vtrans_kernel<<<dim3(16, 64), 256, 0, stream>>>(vbp, vtb);
  // attention: grid (bh, it0-tiles) for XCD K/V locality
  attn_kernel<<<dim3(64, 16), 256, 0, stream>>>(qb, kb, vtb, gate, btab, ctxb);
  // Wo: M=4096 N=1024 K=1024, split-K x4 (256 blocks) -> P0,P1,PW2,PW3
  gemm256<3><<<dim3(16, 4, 4), 512, 0, stream>>>(ctxb, wob, 1024, 1024, 4, 4, 4,
      nullptr, nullptr, nullptr, P0, PW2, PW3, 1024, nullptr, nullptr, nullptr);
  // reduce + bo + residual(x) + LN1 -> hf/hb
  redln_kernel<true, false, 4><<<4096, 256, 0, stream>>>(P0, P1, PW2, PW3, x, bo, nullptr,
      ln1g, ln1b, hf, hb);
  // FF1 + adapter-down fused: N=4352 = 17 x 256 (gelu cols<4096, elu cols>=4096)
  gemm256<2><<<dim3(16, 17, 1), 512, 0, stream>>>(hb, w1ad, 1024, 1024, 16, 16, 1,
      b1, bad, nullptr, nullptr, nullptr, nullptr, 0, ffadp, nullptr, nullptr);
  // FF2+adapter-up via K-concat: K=4352, split-K x4 ({18,18,16,16} K-tiles)
  gemm256<3><<<dim3(16, 4, 4), 512, 0, stream>>>(ffadp, w2au, 4352, 4352, 18, 16, 2,
      nullptr, nullptr, nullptr, P0, P2, P3, 1024, nullptr, nullptr, nullptr);
  redln_kernel<false, true, 4><<<4096, 256, 0, stream>>>(P0, P1, P2, P3, hf, b2, bau,
      ln2g, ln2b, out, nullptr);
}

// Round 4
// 488.063 us; speedup vs baseline: 1.1245x; 1.0889x over previous
//
#include <hip/hip_runtime.h>
#include <cmath>

typedef unsigned short u16;
using short8 = __attribute__((ext_vector_type(8))) short;   // 8 x bf16
using f32x4  = __attribute__((ext_vector_type(4))) float;   // MFMA acc

// ---------- helpers ----------
__device__ __forceinline__ u16 f2bf(float f) {  // fp32 -> bf16 RNE
  union { float f; unsigned u; } c; c.f = f;
  unsigned r = c.u + 0x7fffu + ((c.u >> 16) & 1u);
  return (u16)(r >> 16);
}
__device__ __forceinline__ float bf2f(u16 b) {
  union { unsigned u; float f; } c; c.u = ((unsigned)b) << 16;
  return c.f;
}

__device__ __forceinline__ void gld_lds16(void* lds, const void* g) {
  __builtin_amdgcn_global_load_lds(
      (const __attribute__((address_space(1))) void*)g,
      (__attribute__((address_space(3))) void*)lds, 16, 0, 0);
}

// fast GELU (tanh approx, max err ~1e-3 << bf16 threshold)
__device__ __forceinline__ float gelu_fast(float t) {
  float u = 0.7978845608f * t * (1.f + 0.044715f * t * t);
  float th = 1.f - 2.f / (__expf(2.f * u) + 1.f);
  return 0.5f * t * (1.f + th);
}

// ---------- fp32 -> bf16 convert ----------
__global__ __launch_bounds__(256) void cvt_bf16(const float* __restrict__ in,
                                                u16* __restrict__ out, int n4) {
  int i = blockIdx.x * 256 + threadIdx.x;
  if (i >= n4) return;
  float4 v = ((const float4*)in)[i];
  ushort4 o;
  o.x = f2bf(v.x); o.y = f2bf(v.y); o.z = f2bf(v.z); o.w = f2bf(v.w);
  ((ushort4*)out)[i] = o;
}

// fp32 -> bf16 into strided (padded) rows
__global__ __launch_bounds__(256) void cvt_pad(const float* __restrict__ in,
                                               u16* __restrict__ out,
                                               int incols4, int outstride, int n4) {
  int i = blockIdx.x * 256 + threadIdx.x;
  if (i >= n4) return;
  int row = i / incols4, c = i - row * incols4;
  float4 v = ((const float4*)in)[i];
  ushort4 o;
  o.x = f2bf(v.x); o.y = f2bf(v.y); o.z = f2bf(v.z); o.w = f2bf(v.w);
  *(ushort4*)&out[(size_t)row * outstride + c * 4] = o;
}

// ---------- relative-position bias table ----------
__global__ __launch_bounds__(256) void btab_kernel(const float* __restrict__ rel_embed,
                                                   float* __restrict__ btab) {
  int idx = blockIdx.x * 256 + threadIdx.x;
  if (idx >= 16 * 2048) return;
  int h = idx >> 11;
  int d = idx & 2047;
  if (d >= 2047) return;
  int rel = d - 1023;
  int bucket = (rel > 0) ? 160 : 0;
  int ar = rel < 0 ? -rel : rel;
  if (ar < 80) {
    bucket += ar;
  } else {
    int large = 80 + (int)(logf((float)ar / 80.0f) / 2.3025851f * 80.0f);
    if (large > 159) large = 159;
    bucket += large;
  }
  btab[h * 2048 + d] = rel_embed[bucket * 16 + h];
}

// ---------- gate ----------
__global__ __launch_bounds__(256) void gate_kernel(const float* __restrict__ x,
                                                   const float* __restrict__ Wg,
                                                   const float* __restrict__ bg,
                                                   const float* __restrict__ gc,
                                                   float* __restrict__ gate_out) {
  int gw = blockIdx.x * 4 + (threadIdx.x >> 6);
  int lane = threadIdx.x & 63;
  int s = gw & 1023, bh = gw >> 10, b = bh >> 4, h = bh & 15;
  float wA = Wg[lane] + Wg[64 + lane] + Wg[128 + lane] + Wg[192 + lane];
  float wB = Wg[256 + lane] + Wg[320 + lane] + Wg[384 + lane] + Wg[448 + lane];
  float xv = x[((size_t)(b * 1024 + s)) * 1024 + h * 64 + lane];
  float pa = xv * wA, pb = xv * wB;
  #pragma unroll
  for (int m = 1; m < 64; m <<= 1) {
    pa += __shfl_xor(pa, m, 64);
    pb += __shfl_xor(pb, m, 64);
  }
  if (lane == 0) {
    float bgA = bg[0] + bg[1] + bg[2] + bg[3];
    float bgB = bg[4] + bg[5] + bg[6] + bg[7];
    float ga = 1.f / (1.f + expf(-(pa + bgA)));
    float gb = 1.f / (1.f + expf(-(pb + bgB)));
    gate_out[(size_t)bh * 1024 + s] = ga * (gb * gc[h] - 1.f) + 2.f;
  }
}

// ---------- V transpose: vt[bh][d][s] ----------
__global__ __launch_bounds__(256) void vtrans_kernel(const u16* __restrict__ vb,
                                                     u16* __restrict__ vt) {
  __shared__ u16 tile[64 * 65];
  int bh = blockIdx.y, b = bh >> 4, h = bh & 15;
  int s0 = blockIdx.x * 64;
  int tid = threadIdx.x;
  int r = tid >> 3, c = (tid & 7) * 8;
  #pragma unroll
  for (int p = 0; p < 2; ++p) {
    int s = p * 32 + r;
    uint4 vv = *(const uint4*)&vb[((size_t)(b * 1024 + s0 + s)) * 1024 + h * 64 + c];
    const u16* pv = (const u16*)&vv;
    #pragma unroll
    for (int e = 0; e < 8; ++e) tile[(c + e) * 65 + s] = pv[e];
  }
  __syncthreads();
  int d = tid & 63, jc0 = tid >> 6;
  #pragma unroll
  for (int jc = jc0; jc < 8; jc += 4) {
    u16 tmp[8];
    #pragma unroll
    for (int e = 0; e < 8; ++e) tmp[e] = tile[d * 65 + jc * 8 + e];
    *(uint4*)&vt[((size_t)(bh * 64 + d)) * 1024 + s0 + jc * 8] = *(uint4*)tmp;
  }
}

// ---------- GEMM 256x256, BK=64, 8 waves, 2-phase double-buffer ----------
// Per K-tile: issue next-tile stage (8 x global_load_lds) -> ds_read/MFMA
// current tile (compiler-managed lgkmcnt) -> vmcnt(0) (covered by ~2.5k cycles
// of MFMA since issue) -> one barrier. LDS chunk-XOR swizzle, staging
// pre-swizzles the per-lane GLOBAL address, LDS dest stays linear (rule 21).
// MODE 0: QKV epilogue (seg bias + q*0.125, bf16 x3)
// MODE 2: FF1 gelu (cols<4096, bias0) / adapter elu (cols>=4096, bias1)
// MODE 3: fp32 partials (split-K x4), 4M-float stride, P0|P1 contiguous,
//         kz=2 -> outf2, kz=3 -> outf3
#define VMCNT(n) asm volatile("s_waitcnt vmcnt(" #n ")" ::: "memory")

#define G256_LDA(BUF, KK, MH)                                               \
  af_[0] = *(const short8*)&lds[BUF][0][KK][aBase + (MH) * 2048 + 0];       \
  af_[1] = *(const short8*)&lds[BUF][0][KK][aBase + (MH) * 2048 + 512];     \
  af_[2] = *(const short8*)&lds[BUF][0][KK][aBase + (MH) * 2048 + 1024];    \
  af_[3] = *(const short8*)&lds[BUF][0][KK][aBase + (MH) * 2048 + 1536];
#define G256_LDB(BUF, KK)                                                   \
  bf_[0] = *(const short8*)&lds[BUF][1][KK][bBase + 0];                     \
  bf_[1] = *(const short8*)&lds[BUF][1][KK][bBase + 512];                   \
  bf_[2] = *(const short8*)&lds[BUF][1][KK][bBase + 1024];                  \
  bf_[3] = *(const short8*)&lds[BUF][1][KK][bBase + 1536];
#define G256_MFMA(MH)                                                       \
  _Pragma("unroll") for (int mi = 0; mi < 4; ++mi)                          \
  _Pragma("unroll") for (int ni = 0; ni < 4; ++ni)                          \
    acc[(MH) * 4 + mi][ni] = __builtin_amdgcn_mfma_f32_16x16x32_bf16(       \
        af_[mi], bf_[ni], acc[(MH) * 4 + mi][ni], 0, 0, 0);
#define G256_TILE(BUF)                                                      \
  G256_LDB(BUF, 0)                                                          \
  G256_LDA(BUF, 0, 0)                                                       \
  G256_MFMA(0)                                                              \
  G256_LDA(BUF, 0, 1)                                                       \
  G256_MFMA(1)                                                              \
  G256_LDB(BUF, 1)                                                          \
  G256_LDA(BUF, 1, 0)                                                       \
  G256_MFMA(0)                                                              \
  G256_LDA(BUF, 1, 1)                                                       \
  G256_MFMA(1)

template <int MODE>
__global__ __launch_bounds__(512, 2) void gemm256(
    const u16* __restrict__ A, const u16* __restrict__ Bw,
    int lda, int ldb, int kt_hi, int kt_lo, int z_hi,
    const float* __restrict__ bias0, const float* __restrict__ bias1,
    const float* __restrict__ bias2,
    float* __restrict__ outf, float* __restrict__ outf2,
    float* __restrict__ outf3, int ldo,
    u16* __restrict__ ob0, u16* __restrict__ ob1, u16* __restrict__ ob2) {
  __shared__ __align__(16) u16 lds[2][2][2][8192];

  const int tid = threadIdx.x;
  const int lane = tid & 63, wave = tid >> 6;
  const int quad = lane >> 4, l16 = lane & 15;
  const int wm = wave >> 2, wn = wave & 3;

  // XCD-aware bijective swizzle (all grids are multiples of 8 blocks)
  const int gx = gridDim.x, gy = gridDim.y;
  int flat = blockIdx.x + gx * (blockIdx.y + gy * blockIdx.z);
  const int cpx = (gx * gy * gridDim.z) >> 3;
  flat = (flat & 7) * cpx + (flat >> 3);
  const int bmi = flat % gx;
  int rest = flat / gx;
  const int bni = rest % gy;
  const int kz = rest / gy;

  const int bm = bmi * 256, bn = bni * 256;
  const int nkt = (kz < z_hi) ? kt_hi : kt_lo;   // must be EVEN
  const int ktb = (kz < z_hi) ? kz * kt_hi : z_hi * kt_hi + (kz - z_hi) * kt_lo;

  // staging geometry: lane l stages row (wave*16 + l/4) (+128 for 2nd load),
  // global 16B chunk (l&3)^((row>>1)&3) -> linear LDS dest.
  const int srow = wave * 16 + (lane >> 2);
  const int sk = (((lane & 3) ^ ((lane >> 3) & 3)) << 3);
  const u16* aG = A + (size_t)(bm + srow) * lda + (size_t)ktb * 64 + sk;
  const u16* bG = Bw + (size_t)(bn + srow) * ldb + (size_t)ktb * 64 + sk;
  const size_t aS = (size_t)128 * lda, bS = (size_t)128 * ldb;

  // frag read bases (u16 index inside one [8192] region)
  const int xsw = ((quad ^ ((l16 >> 1) & 3)) << 3);
  const int aBase = (wm * 128 + l16) * 32 + xsw;
  const int bBase = (wn * 64 + l16) * 32 + xsw;

  auto stA = [&](int buf, int kh, int kt) {
    const u16* g = aG + kt * 64 + kh * 32;
    u16* d = (u16*)&lds[buf][0][kh][wave * 512];
    gld_lds16(d, g);
    gld_lds16(d + 4096, g + aS);
  };
  auto stB = [&](int buf, int kh, int kt) {
    const u16* g = bG + kt * 64 + kh * 32;
    u16* d = (u16*)&lds[buf][1][kh][wave * 512];
    gld_lds16(d, g);
    gld_lds16(d + 4096, g + bS);
  };

  f32x4 acc[8][4] = {};
  short8 af_[4], bf_[4];

  // prologue: stage tile 0 -> buf0, drain, barrier
  stA(0, 0, 0); stB(0, 0, 0); stA(0, 1, 0); stB(0, 1, 0);
  VMCNT(0);
  __builtin_amdgcn_s_barrier();

  for (int J = 0; J < (nkt >> 1); ++J) {
    {  // even tile t=2J in buf0; prefetch t+1 -> buf1 (always exists)
      const int t1 = 2 * J + 1;
      stA(1, 0, t1); stB(1, 0, t1); stA(1, 1, t1); stB(1, 1, t1);
      G256_TILE(0)
      VMCNT(0);
      __builtin_amdgcn_s_barrier();
    }
    {  // odd tile t=2J+1 in buf1; prefetch t+2 -> buf0 (if exists)
      const int t2 = 2 * J + 2;
      if (t2 < nkt) { stA(0, 0, t2); stB(0, 0, t2); stA(0, 1, t2); stB(0, 1, t2); }
      G256_TILE(1)
      VMCNT(0);
      __builtin_amdgcn_s_barrier();
    }
  }

  const int m0 = bm + wm * 128 + quad * 4;
  const int n0 = bn + wn * 64 + l16;

  if constexpr (MODE == 0) {
    const int seg = bn >> 10;  // tile never straddles a 1024 segment
    const float* bs = seg == 0 ? bias0 : (seg == 1 ? bias1 : bias2);
    u16* dst = seg == 0 ? ob0 : (seg == 1 ? ob1 : ob2);
    const float sc = seg == 0 ? 0.125f : 1.0f;
    const int nb = (bn & 1023) + wn * 64 + l16;
    #pragma unroll
    for (int a = 0; a < 8; ++a)
      #pragma unroll
      for (int ni = 0; ni < 4; ++ni) {
        int nn = nb + ni * 16;
        float bv = bs[nn];
        #pragma unroll
        for (int r = 0; r < 4; ++r) {
          int m = m0 + a * 16 + r;
          dst[(size_t)m * 1024 + nn] = f2bf((acc[a][ni][r] + bv) * sc);
        }
      }
  } else if constexpr (MODE == 2) {
    const bool is_gelu = (bn < 4096);   // block-uniform
    #pragma unroll
    for (int a = 0; a < 8; ++a)
      #pragma unroll
      for (int ni = 0; ni < 4; ++ni) {
        int nn = n0 + ni * 16;
        float bv = is_gelu ? bias0[nn] : bias1[nn - 4096];
        #pragma unroll
        for (int r = 0; r < 4; ++r) {
          int m = m0 + a * 16 + r;
          float t = acc[a][ni][r] + bv;
          float res;
          if (is_gelu) res = gelu_fast(t);
          else         res = t > 0.f ? t : (__expf(t) - 1.f);
          ob0[(size_t)m * 4352 + nn] = f2bf(res);
        }
      }
  } else {  // MODE 3: fp32 partials
    float* op = (kz == 0) ? outf
              : (kz == 1) ? outf + 4194304
              : (kz == 2) ? outf2 : outf3;
    #pragma unroll
    for (int a = 0; a < 8; ++a)
      #pragma unroll
      for (int ni = 0; ni < 4; ++ni) {
        int nn = n0 + ni * 16;
        #pragma unroll
        for (int r = 0; r < 4; ++r)
          op[(size_t)(m0 + a * 16 + r) * ldo + nn] = acc[a][ni][r];
      }
  }
}

// ---------- flash attention: LDS-staged K/V, double-buffered (2-phase) ----------
// Best-measured structure (R1, 96us) + the missing pipeline: global_load_lds
// for tile jt+1 is issued BEFORE compute of tile jt and drains at the
// end-of-iteration vmcnt(0)+barrier -> staging latency hides under
// QK^T+softmax+PV (~1500cy). gld_lds issue points are architecturally pinned
// (unlike reg prefetch, which the compiler sank in R3: VGPR=84 proved it).
// Grid (bh, it0): flat%8 = bh%8 -> one XCD per (b,h), K/V HBM-fetched once
// per XCD (R3-verified: FETCH 70->13MB). Q in regs; Ps repack per-wave.
__global__ __launch_bounds__(256) void attn_kernel(
    const u16* __restrict__ qb, const u16* __restrict__ kb, const u16* __restrict__ vt,
    const float* __restrict__ gate, const float* __restrict__ btab,
    u16* __restrict__ ctxb) {
  __shared__ __align__(16) u16 Ks[2][64 * 64];
  __shared__ __align__(16) u16 Vs[2][64 * 64];
  __shared__ __align__(16) u16 Ps[4][16 * 64];
  __shared__ u16 btl[2048];
  __shared__ float gbuf[64];

  const int tid = threadIdx.x;
  const int lane = tid & 63, wave = tid >> 6;
  const int quad = lane >> 4, l16 = lane & 15;
  const int bh = blockIdx.x, b = bh >> 4, h = bh & 15;
  const int it0 = blockIdx.y * 64;
  const int sr = lane & 15;
  const int skc = (lane >> 4) * 8;

  // stage K/V tile jt into buffer buf (4 x global_load_lds per wave-slab)
  auto stage = [&](int buf, int jt) {
    const int j0 = jt * 64;
    #pragma unroll
    for (int hf = 0; hf < 2; ++hf) {
      gld_lds16(&Ks[buf][wave * 1024 + hf * 512],
                &kb[((size_t)(b * 1024 + j0 + wave * 16 + sr)) * 1024 + h * 64 + hf * 32 + skc]);
      gld_lds16(&Vs[buf][wave * 1024 + hf * 512],
                &vt[((size_t)(bh * 64 + wave * 16 + sr)) * 1024 + j0 + hf * 32 + skc]);
    }
  };

  for (int idx = tid; idx < 2047; idx += 256) btl[idx] = f2bf(btab[h * 2048 + idx]);
  if (tid < 64) gbuf[tid] = gate[(size_t)bh * 1024 + it0 + tid];

  // Q fragments held in registers for the whole kernel
  short8 aq[2];
  #pragma unroll
  for (int c = 0; c < 2; ++c)
    aq[c] = *(const short8*)&qb[((size_t)(b * 1024 + it0 + wave * 16 + l16)) * 1024 +
                                h * 64 + c * 32 + quad * 8];

  f32x4 oacc[4] = {};
  float mrow[4], lrow[4];
  #pragma unroll
  for (int r = 0; r < 4; ++r) { mrow[r] = -1e30f; lrow[r] = 0.f; }

  stage(0, 0);
  __syncthreads();   // drains vm+lgkm: tile0 + btl/gbuf ready

  for (int jt = 0; jt < 16; ++jt) {
    const int cur = jt & 1;
    const int j0 = jt * 64;
    if (jt < 15) stage(cur ^ 1, jt + 1);   // prefetch next tile (drains at loop tail)

    f32x4 sacc[4] = {};
    #pragma unroll
    for (int c = 0; c < 2; ++c) {
      #pragma unroll
      for (int nt = 0; nt < 4; ++nt) {
        short8 bk8 = *(const short8*)&Ks[cur][nt * 1024 + (c * 4 + quad) * 128 + l16 * 8];
        sacc[nt] = __builtin_amdgcn_mfma_f32_16x16x32_bf16(aq[c], bk8, sacc[nt], 0, 0, 0);
      }
    }

    float sc[4][4], mt[4];
    #pragma unroll
    for (int r = 0; r < 4; ++r) {
      int i_loc = wave * 16 + quad * 4 + r;
      int i_glob = it0 + i_loc;
      float g = gbuf[i_loc];
      float mx = -1e30f;
      #pragma unroll
      for (int nt = 0; nt < 4; ++nt) {
        int j = j0 + nt * 16 + l16;
        float s = sacc[nt][r] + g * bf2f(btl[j - i_glob + 1023]);
        sc[nt][r] = s;
        mx = fmaxf(mx, s);
      }
      mt[r] = mx;
    }
    #pragma unroll
    for (int m = 1; m < 16; m <<= 1)
      #pragma unroll
      for (int r = 0; r < 4; ++r) mt[r] = fmaxf(mt[r], __shfl_xor(mt[r], m, 64));

    float alpha[4], ls[4];
    #pragma unroll
    for (int r = 0; r < 4; ++r) {
      float mnew = fmaxf(mrow[r], mt[r]);
      alpha[r] = __expf(mrow[r] - mnew);
      mrow[r] = mnew;
      float lsum = 0.f;
      #pragma unroll
      for (int nt = 0; nt < 4; ++nt) {
        float p = __expf(sc[nt][r] - mnew);
        sc[nt][r] = p;
        lsum += p;
      }
      ls[r] = lsum;
    }
    #pragma unroll
    for (int m = 1; m < 16; m <<= 1)
      #pragma unroll
      for (int r = 0; r < 4; ++r) ls[r] += __shfl_xor(ls[r], m, 64);
    #pragma unroll
    for (int r = 0; r < 4; ++r) lrow[r] = lrow[r] * alpha[r] + ls[r];

    // P -> bf16 A-frag repack via per-wave LDS (same-wave RAW, lgkmcnt only)
    #pragma unroll
    for (int nt = 0; nt < 4; ++nt)
      #pragma unroll
      for (int r = 0; r < 4; ++r)
        Ps[wave][(nt * 2 + (l16 >> 3)) * 128 + (quad * 4 + r) * 8 + (l16 & 7)] = f2bf(sc[nt][r]);

    #pragma unroll
    for (int dt = 0; dt < 4; ++dt)
      #pragma unroll
      for (int r = 0; r < 4; ++r) oacc[dt][r] *= alpha[r];

    #pragma unroll
    for (int c = 0; c < 2; ++c) {
      short8 ap = *(const short8*)&Ps[wave][(c * 4 + quad) * 128 + l16 * 8];
      #pragma unroll
      for (int dt = 0; dt < 4; ++dt) {
        short8 bv8 = *(const short8*)&Vs[cur][dt * 1024 + (c * 4 + quad) * 128 + l16 * 8];
        oacc[dt] = __builtin_amdgcn_mfma_f32_16x16x32_bf16(ap, bv8, oacc[dt], 0, 0, 0);
      }
    }

    VMCNT(0);                          // next tile's gld_lds landed
    __builtin_amdgcn_s_barrier();      // all waves done reading cur
  }

  #pragma unroll
  for (int dt = 0; dt < 4; ++dt)
    #pragma unroll
    for (int r = 0; r < 4; ++r) {
      int i_loc = wave * 16 + quad * 4 + r;
      int d = dt * 16 + l16;
      float o = oacc[dt][r] / lrow[r];
      ctxb[((size_t)(b * 1024 + it0 + i_loc)) * 1024 + h * 64 + d] = f2bf(o);
    }
}

// ---------- fused reduce(+resid+bias) + LayerNorm (NP partials) ----------
template <bool WRITE_BF16, bool TWO_BIAS, int NP>
__global__ __launch_bounds__(256) void redln_kernel(
    const float* __restrict__ p0, const float* __restrict__ p1,
    const float* __restrict__ p2, const float* __restrict__ p3,
    const float* __restrict__ extra, const float* __restrict__ bias,
    const float* __restrict__ bias2,
    const float* __restrict__ g, const float* __restrict__ bta,
    float* __restrict__ outf, u16* __restrict__ outb) {
  __shared__ float red[8];
  int row = blockIdx.x, tid = threadIdx.x;
  int lane = tid & 63, wave = tid >> 6;
  size_t base = (size_t)row * 1024 + tid * 4;
  float4 a = *(const float4*)&p0[base];
  float4 bb = *(const float4*)&p1[base];
  float4 c = *(const float4*)&extra[base];
  float4 d = *(const float4*)&bias[tid * 4];
  float4 v;
  v.x = a.x + bb.x + c.x + d.x;
  v.y = a.y + bb.y + c.y + d.y;
  v.z = a.z + bb.z + c.z + d.z;
  v.w = a.w + bb.w + c.w + d.w;
  if (NP == 4) {
    float4 e2 = *(const float4*)&p2[base];
    float4 e3 = *(const float4*)&p3[base];
    v.x += e2.x + e3.x; v.y += e2.y + e3.y;
    v.z += e2.z + e3.z; v.w += e2.w + e3.w;
  }
  if (TWO_BIAS) {
    float4 d2 = *(const float4*)&bias2[tid * 4];
    v.x += d2.x; v.y += d2.y; v.z += d2.z; v.w += d2.w;
  }
  float s = v.x + v.y + v.z + v.w;
  #pragma unroll
  for (int m = 1; m < 64; m <<= 1) s += __shfl_xor(s, m, 64);
  if (lane == 0) red[wave] = s;
  __syncthreads();
  float mean = (red[0] + red[1] + red[2] + red[3]) * (1.f / 1024.f);
  float d0 = v.x - mean, d1 = v.y - mean, d2 = v.z - mean, d3 = v.w - mean;
  float sq = d0 * d0 + d1 * d1 + d2 * d2 + d3 * d3;
  #pragma unroll
  for (int m = 1; m < 64; m <<= 1) sq += __shfl_xor(sq, m, 64);
  if (lane == 0) red[4 + wave] = sq;
  __syncthreads();
  float var = (red[4] + red[5] + red[6] + red[7]) * (1.f / 1024.f);
  float rstd = rsqrtf(var + 1e-5f);
  float dd[4] = {d0, d1, d2, d3};
  #pragma unroll
  for (int e = 0; e < 4; ++e) {
    int cidx = tid * 4 + e;
    float val = dd[e] * rstd * g[cidx] + bta[cidx];
    outf[(size_t)row * 1024 + cidx] = val;
    if (WRITE_BF16) outb[(size_t)row * 1024 + cidx] = f2bf(val);
  }
}

// ---------- launch ----------
extern "C" void kernel_launch(void* const* d_in, const int* in_sizes, int n_in,
                              void* d_out, int out_size, void* d_ws, size_t ws_size,
                              hipStream_t stream) {
  const float* x    = (const float*)d_in[0];
  const float* Wq   = (const float*)d_in[1];  const float* bq  = (const float*)d_in[2];
  const float* Wk   = (const float*)d_in[3];  const float* bk  = (const float*)d_in[4];
  const float* Wv   = (const float*)d_in[5];  const float* bv  = (const float*)d_in[6];
  const float* Wo   = (const float*)d_in[7];  const float* bo  = (const float*)d_in[8];
  const float* Wg   = (const float*)d_in[9];  const float* bg  = (const float*)d_in[10];
  const float* gc   = (const float*)d_in[11];
  const float* rel  = (const float*)d_in[12];
  const float* ln1g = (const float*)d_in[13]; const float* ln1b = (const float*)d_in[14];
  const float* W1   = (const float*)d_in[15]; const float* b1  = (const float*)d_in[16];
  const float* W2   = (const float*)d_in[17]; const float* b2  = (const float*)d_in[18];
  const float* ln2g = (const float*)d_in[19]; const float* ln2b = (const float*)d_in[20];
  const float* Wad  = (const float*)d_in[21]; const float* bad = (const float*)d_in[22];
  const float* Wau  = (const float*)d_in[23]; const float* bau = (const float*)d_in[24];
  float* out = (float*)d_out;

  char* ws = (char*)d_ws;
  const size_t MB = 1ull << 20;
  const size_t KB = 1ull << 10;
  (void)n_in; (void)in_sizes; (void)out_size;

  const bool big = ws_size >= (135ull << 20);

  u16 *xb, *wqkv, *qb, *kb, *vbp, *vtb, *ctxb, *wob, *w1ad, *w2au, *ffadp, *hb;
  float *gate, *btab, *P0, *P1, *P2, *P3, *hf;
  xb    = (u16*)(ws + 0 * MB);
  wqkv  = (u16*)(ws + 8 * MB);
  ffadp = (u16*)(ws + 0 * MB);
  P0    = (float*)(ws + 34 * MB);
  P1    = (float*)(ws + 50 * MB);
  // Wo split-4 partials kz=2,3 -> ws 0..32MB (xb/wqkv dead by Wo)
  float* PW2 = (float*)(ws + 0 * MB);
  float* PW3 = (float*)(ws + 16 * MB);
  if (big) {
    P2   = (float*)(ws + 66 * MB);
    P3   = (float*)(ws + 82 * MB);
    qb   = (u16*)(ws + 66 * MB);
    kb   = (u16*)(ws + 74 * MB);
    vbp  = (u16*)(ws + 82 * MB);
    vtb  = (u16*)(ws + 90 * MB);
    hb   = (u16*)(ws + 82 * MB);      // after redln1 (vbp dead); dead before FF2 writes P3
    ctxb = (u16*)(ws + 98 * MB);
    hf   = (float*)(ws + 98 * MB);    // after redln1 (ctxb dead)
    wob  = (u16*)(ws + 114 * MB);
    w1ad = (u16*)(ws + 116 * MB);
    w2au = (u16*)(ws + 125 * MB);
    gate = (float*)(ws + 133 * MB + 512 * KB);
    btab = (float*)(ws + 133 * MB + 768 * KB);
  } else {
    qb   = (u16*)(ws + 14 * MB);
    kb   = (u16*)(ws + 22 * MB);
    vbp  = (u16*)(ws + 30 * MB);
    vtb  = (u16*)(ws + 38 * MB);
    gate = (float*)(ws + 46 * MB);
    btab = (float*)(ws + 46 * MB + 256 * KB);
    ctxb = (u16*)(ws + 66 * MB);
    wob  = (u16*)(ws + 74 * MB);
    w1ad = (u16*)(ws + 76 * MB);
    w2au = (u16*)(ws + 85 * MB);
    hf   = (float*)(ws + 94 * MB);
    hb   = (u16*)(ws + 110 * MB);
    P2   = (float*)(ws + 66 * MB);    // over ctxb (dead at FF2 time)
    P3   = (float*)(ws + 14 * MB);    // over qb/kb (dead at FF2 time)
  }

  auto cvt = [&](const float* src, u16* dst, int n) {
    cvt_bf16<<<(n / 4 + 255) / 256, 256, 0, stream>>>(src, dst, n / 4);
  };
  cvt(x, xb, 4096 * 1024);
  cvt(Wq, wqkv,               1024 * 1024);
  cvt(Wk, wqkv + 1024 * 1024, 1024 * 1024);
  cvt(Wv, wqkv + 2 * 1024 * 1024, 1024 * 1024);
  cvt(Wo, wob, 1024 * 1024);
  cvt(W1, w1ad, 4096 * 1024);
  cvt(Wad, w1ad + 4096 * 1024, 256 * 1024);
  cvt_pad<<<(1024 * 1024 + 255) / 256, 256, 0, stream>>>(W2, w2au, 1024, 4352, 1024 * 1024);
  cvt_pad<<<(64 * 1024 + 255) / 256, 256, 0, stream>>>(Wau, w2au + 4096, 64, 4352, 64 * 1024);

  btab_kernel<<<128, 256, 0, stream>>>(rel, btab);
  gate_kernel<<<16384, 256, 0, stream>>>(x, Wg, bg, gc, gate);

  // QKV: M=4096 N=3072 K=1024 (192 blocks)
  gemm256<0><<<dim3(16, 12, 1), 512, 0, stream>>>(xb, wqkv, 1024, 1024, 16, 16, 1,
      bq, bk, bv, nullptr, nullptr, nullptr, 0, qb, kb, vbp);
  vtrans_kernel<<<dim3(16, 64), 256, 0, stream>>>(vbp, vtb);
  // attention: grid (bh, it0-tiles) for XCD K/V locality
  attn_kernel<<<dim3(64, 16), 256, 0, stream>>>(qb, kb, vtb, gate, btab, ctxb);
  // Wo: M=4096 N=1024 K=1024, split-K x4 (256 blocks) -> P0,P1,PW2,PW3
  gemm256<3><<<dim3(16, 4, 4), 512, 0, stream>>>(ctxb, wob, 1024, 1024, 4, 4, 4,
      nullptr, nullptr, nullptr, P0, PW2, PW3, 1024, nullptr, nullptr, nullptr);
  // reduce + bo + residual(x) + LN1 -> hf/hb
  redln_kernel<true, false, 4><<<4096, 256, 0, stream>>>(P0, P1, PW2, PW3, x, bo, nullptr,
      ln1g, ln1b, hf, hb);
  // FF1 + adapter-down fused: N=4352 = 17 x 256 (gelu cols<4096, elu cols>=4096)
  gemm256<2><<<dim3(16, 17, 1), 512, 0, stream>>>(hb, w1ad, 1024, 1024, 16, 16, 1,
      b1, bad, nullptr, nullptr, nullptr, nullptr, 0, ffadp, nullptr, nullptr);
  // FF2+adapter-up via K-concat: K=4352, split-K x4 ({18,18,16,16} K-tiles)
  gemm256<3><<<dim3(16, 4, 4), 512, 0, stream>>>(ffadp, w2au, 4352, 4352, 18, 16, 2,
      nullptr, nullptr, nullptr, P0, P2, P3, 1024, nullptr, nullptr, nullptr);
  redln_kernel<false, true, 4><<<4096, 256, 0, stream>>>(P0, P1, P2, P3, hf, b2, bau,
      ln2g, ln2b, out, nullptr);
}